// Round 6
// baseline (766.531 us; speedup 1.0000x reference)
//
#include <hip/hip_runtime.h>
#include <hip/hip_bf16.h>

constexpr int NN    = 30000;   // total nodes
constexpr int NCELL = 66;
constexpr int NF    = 256;     // features
constexpr int CAP   = 80;      // bucket capacity per col (in-deg mean 32, P(>80)~1e-8)
constexpr float EPS = 1e-5f;

using bf16x8 = __attribute__((ext_vector_type(8))) short;   // 8 bf16 = 4 VGPRs
using f32x4  = __attribute__((ext_vector_type(4))) float;
using f32x2  = __attribute__((ext_vector_type(2))) float;

__device__ __forceinline__ float bf2f(unsigned short u) {
    return __uint_as_float(((unsigned)u) << 16);
}
__device__ __forceinline__ unsigned short f2bf(float f) {
    __hip_bfloat16 h = __float2bfloat16(f);   // RNE
    return *reinterpret_cast<unsigned short*>(&h);
}
// accumulate 8 bf16 features packed in a float4 (bit halves) into 4x f32x2 (pk_fma)
__device__ __forceinline__ void acc8v(f32x2* acc, float4 u, float w) {
    unsigned a = __float_as_uint(u.x), b = __float_as_uint(u.y);
    unsigned c = __float_as_uint(u.z), d = __float_as_uint(u.w);
    f32x2 wv; wv[0] = w; wv[1] = w;
    f32x2 e0; e0[0] = __uint_as_float(a << 16); e0[1] = __uint_as_float(a & 0xffff0000u);
    f32x2 e1; e1[0] = __uint_as_float(b << 16); e1[1] = __uint_as_float(b & 0xffff0000u);
    f32x2 e2; e2[0] = __uint_as_float(c << 16); e2[1] = __uint_as_float(c & 0xffff0000u);
    f32x2 e3; e3[0] = __uint_as_float(d << 16); e3[1] = __uint_as_float(d & 0xffff0000u);
    acc[0] += wv * e0;
    acc[1] += wv * e1;
    acc[2] += wv * e2;
    acc[3] += wv * e3;
}
// scalar variant for epilogue self-loop add
__device__ __forceinline__ void acc8(float* acc, float4 u, float w) {
    unsigned a = __float_as_uint(u.x), b = __float_as_uint(u.y);
    unsigned c = __float_as_uint(u.z), d = __float_as_uint(u.w);
    acc[0] += w * __uint_as_float(a << 16);
    acc[1] += w * __uint_as_float(a & 0xffff0000u);
    acc[2] += w * __uint_as_float(b << 16);
    acc[3] += w * __uint_as_float(b & 0xffff0000u);
    acc[4] += w * __uint_as_float(c << 16);
    acc[5] += w * __uint_as_float(c & 0xffff0000u);
    acc[6] += w * __uint_as_float(d << 16);
    acc[7] += w * __uint_as_float(d & 0xffff0000u);
}

// ---------------- init: fill/sums = 0 ----------------
__global__ void k_init(int* fill, float* sums) {
    int i = blockIdx.x * 256 + threadIdx.x;
    if (i < NN) fill[i] = 0;
    if (i < 2 * NF) sums[i] = 0.0f;
}

__global__ void k_zero_stats(float* sums) {
    int i = threadIdx.x;
    if (i < 2 * NF) sums[i] = 0.0f;
}

// ---------------- convert W (f32, o-major k-contig) -> bf16 ----------------
__global__ void k_cvtw(const float4* __restrict__ W, ushort4* __restrict__ Wh) {
    int idx = blockIdx.x * 256 + threadIdx.x;
    if (idx >= NF * NF / 4) return;
    float4 v = W[idx];
    ushort4 o;
    o.x = f2bf(v.x); o.y = f2bf(v.y); o.z = f2bf(v.z); o.w = f2bf(v.w);
    Wh[idx] = o;
}

// ------- scatter edges into fixed-capacity buckets: 1 atomic + one 4B nt store -----
// (round-0 form, measured best: nt store 77us; cached store 85us / 58MB writes)
__global__ void k_scatter(const int* __restrict__ ei, const float* __restrict__ ew,
                          int* fill, unsigned* __restrict__ bkt, int E) {
    int e = blockIdx.x * 256 + threadIdx.x;
    if (e >= E) return;
    int row = ei[e];
    int col = ei[E + e];
    unsigned q = (unsigned)(ew[e] * 65536.0f);        // trunc; ew<1 => q<=65535
    int pos = atomicAdd(&fill[col], 1);
    unsigned v = ((unsigned)row) | (q << 16);
    __builtin_nontemporal_store(v, &bkt[(size_t)col * CAP + pos]);
}

// ------- per-col degree from bucket (exact int sum of ewq), emit scales -----------
// s1 = dinv^2 (hops 1-2 row scale = D^-1), s2 = dinv (hop-3 scale & input pre-scale)
__global__ void k_deg(const unsigned* __restrict__ bkt, const int* __restrict__ fill,
                      float* __restrict__ s1, float* __restrict__ s2) {
    int i = blockIdx.x * 256 + threadIdx.x;
    if (i >= NN) return;
    int cnt = fill[i];
    unsigned sq = 0;
    const unsigned* p = bkt + (size_t)i * CAP;
    for (int e = 0; e < cnt; e++) sq += (p[e] >> 16);
    float deg = 1.0f + (float)sq * (1.0f / 65536.0f);
    float di = rsqrtf(deg);
    s2[i] = di;
    s1[i] = di * di;
}

// ---------------- concat (cell ++ sub), pre-scale by dinv, f32 -> bf16 ------------
__global__ void k_concat_h(const float4* __restrict__ cell, const float4* __restrict__ sub,
                           const float* __restrict__ dinv, ushort4* __restrict__ xh) {
    int idx = blockIdx.x * 256 + threadIdx.x;          // float4 index
    if (idx >= NN * (NF / 4)) return;
    const int CELL4 = NCELL * (NF / 4);
    float4 v = (idx < CELL4) ? cell[idx] : sub[idx - CELL4];
    float di = dinv[idx >> 6];
    ushort4 o;
    o.x = f2bf(v.x * di); o.y = f2bf(v.y * di);
    o.z = f2bf(v.z * di); o.w = f2bf(v.w * di);
    xh[idx] = o;
}

// ----- one hop, ONE 64-feature chunk: t[c] = (A+I) x[c], row-scale; bf16 io -------
// L2-residency by construction: each kernel touches only chunk c of x ->
// per-XCD gather working set = 30000 x 128B = 3.75MB < 4MB L2. Stream-serialized
// kernel boundaries enforce that ALL co-resident blocks (on every XCD) gather
// from the same chunk -- no dispatch-order or XCD-mapping bets (R2/R4 lessons).
// Wave = node: lanes = 8 edge-groups x 8 float4-slots; 16 edges in flight via
// bounds-predicated 2-deep batches (OOB -> w=0, harmless row-0 read).
// Metas nt-loaded (don't evict the hot chunk); output nt-stored (full 128B lines,
// next hop reads them mostly cross-XCD via L3 anyway).
__global__ __launch_bounds__(256) void k_prop_c(const ushort* __restrict__ xin,
                                                ushort* __restrict__ xout,
                                                const int* __restrict__ fill,
                                                const unsigned* __restrict__ bkt,
                                                const float* __restrict__ scale,
                                                int c) {
    int n    = blockIdx.x * 4 + (threadIdx.x >> 6);
    int lane = threadIdx.x & 63;
    int eg   = lane >> 3;                // edge group 0..7
    int f    = lane & 7;                 // float4 slot within the 128B chunk
    const float4* xl = (const float4*)xin + c * 8 + f;   // row r at xl[r*32]
    const unsigned* base = bkt + (size_t)n * CAP;
    int cnt = fill[n];
    float4 uself = xl[n * 32];           // early: self-loop chunk (in working set)
    float sc = scale[n];                 // early: row scale
    f32x2 acc[4];
    #pragma unroll
    for (int i = 0; i < 4; i++) { acc[i][0] = 0.f; acc[i][1] = 0.f; }
    for (int e0 = 0; e0 < cnt; e0 += 16) {               // 16 edges (2-deep) in flight
        int e = e0 + eg;
        unsigned m0 = (e < cnt)     ? __builtin_nontemporal_load(base + e)     : 0u;
        unsigned m1 = (e + 8 < cnt) ? __builtin_nontemporal_load(base + e + 8) : 0u;
        int r0 = (int)(m0 & 0xffffu), r1 = (int)(m1 & 0xffffu);
        float w0 = (float)(m0 >> 16) * (1.0f / 65536.0f);
        float w1 = (float)(m1 >> 16) * (1.0f / 65536.0f);
        float4 u0 = xl[r0 * 32];
        float4 u1 = xl[r1 * 32];
        acc8v(acc, u0, w0);
        acc8v(acc, u1, w1);
    }
    float accs[8];
    #pragma unroll
    for (int i = 0; i < 4; i++) { accs[2 * i] = acc[i][0]; accs[2 * i + 1] = acc[i][1]; }
    // reduce across the 8 edge groups (lane bits 3..5)
    #pragma unroll
    for (int i = 0; i < 8; i++) {
        accs[i] += __shfl_xor(accs[i], 8);
        accs[i] += __shfl_xor(accs[i], 16);
        accs[i] += __shfl_xor(accs[i], 32);
    }
    if (eg == 0) {
        acc8(accs, uself, 1.0f);           // self loop, raw weight 1
        #pragma unroll
        for (int i = 0; i < 8; i++) accs[i] *= sc;
        unsigned p0 = ((unsigned)f2bf(accs[1]) << 16) | f2bf(accs[0]);
        unsigned p1 = ((unsigned)f2bf(accs[3]) << 16) | f2bf(accs[2]);
        unsigned p2 = ((unsigned)f2bf(accs[5]) << 16) | f2bf(accs[4]);
        unsigned p3 = ((unsigned)f2bf(accs[7]) << 16) | f2bf(accs[6]);
        f32x4 o;
        o[0] = __uint_as_float(p0); o[1] = __uint_as_float(p1);
        o[2] = __uint_as_float(p2); o[3] = __uint_as_float(p3);
        __builtin_nontemporal_store(o, (f32x4*)xout + n * 32 + c * 8 + f);
    }
}

// ------- y[m][o] = PReLU(bias[o] + sum_k A[m][k] W[o][k]) -> f32, + BN stats ------
// r9-verified: wave = 16 rows x full 256 cols (acc[16]); stats via LDS block-reduce
// (4 waves) -> 512 atomics/block. Invalid pad wave guarded (no early return).
__global__ __launch_bounds__(256) void k_gemm_fused(const short* __restrict__ A,  // NN x 256 bf16
                                                    const short* __restrict__ B,  // 256 x 256 bf16 (W)
                                                    const float* __restrict__ bias,
                                                    const float* __restrict__ pw,
                                                    float* __restrict__ y,        // NN x 256 f32
                                                    float* __restrict__ sums) {
    constexpr int RT = NN / 16;        // 1875 row tiles
    int w    = threadIdx.x >> 6;       // wave in block
    int lane = threadIdx.x & 63;
    int rt   = blockIdx.x * 4 + w;     // 4 row tiles per block
    int ml   = lane & 15;              // row in tile (A) / col in 16-tile (B, D)
    int q    = lane >> 4;              // quad: A/B k = q*8+j, D row = q*4+r
    bool valid = rt < RT;
    __shared__ float red[2][4][NF];    // [s|s2][wave][col] = 8 KB
    f32x4 acc[16];
    #pragma unroll
    for (int i = 0; i < 16; i++) acc[i] = (f32x4){0.f, 0.f, 0.f, 0.f};
    if (valid) {
        const short* arow = A + (rt * 16 + ml) * NF + q * 8;
        #pragma unroll
        for (int ks = 0; ks < 8; ks++) {
            bf16x8 a = *(const bf16x8*)(arow + ks * 32);
            #pragma unroll
            for (int nt = 0; nt < 16; nt++) {
                bf16x8 b = *(const bf16x8*)(B + (nt * 16 + ml) * NF + ks * 32 + q * 8);
                acc[nt] = __builtin_amdgcn_mfma_f32_16x16x32_bf16(a, b, acc[nt], 0, 0, 0);
            }
        }
    }
    #pragma unroll
    for (int nt = 0; nt < 16; nt++) {
        int col = nt * 16 + ml;
        float s = 0.f, s2 = 0.f;
        if (valid) {
            float bb = bias[col];
            float pc = pw[col];
            #pragma unroll
            for (int r = 0; r < 4; r++) {
                float v = acc[nt][r] + bb;
                v = (v >= 0.f) ? v : pc * v;
                s += v; s2 += v * v;
                y[(rt * 16 + q * 4 + r) * NF + col] = v;
            }
        }
        s  += __shfl_xor(s, 16);  s  += __shfl_xor(s, 32);
        s2 += __shfl_xor(s2, 16); s2 += __shfl_xor(s2, 32);
        if (lane < 16) { red[0][w][col] = s; red[1][w][col] = s2; }
    }
    __syncthreads();
    int t = threadIdx.x;               // t = col, all 256 threads
    float v0 = red[0][0][t] + red[0][1][t] + red[0][2][t] + red[0][3][t];
    float v1 = red[1][0][t] + red[1][1][t] + red[1][2][t] + red[1][3][t];
    atomicAdd(&sums[t], v0);
    atomicAdd(&sums[NF + t], v1);
}

// ---------------- finalize BN scale/shift ----------------
__global__ void k_finalize(const float* __restrict__ sums, const float* __restrict__ gamma,
                           const float* __restrict__ beta, float* __restrict__ ss) {
    int t = threadIdx.x;
    float mean = sums[t] / (float)NN;
    float var = sums[NF + t] / (float)NN - mean * mean;
    if (var < 0.f) var = 0.f;
    float istd = rsqrtf(var + EPS);
    float sc = gamma[t] * istd;
    ss[t] = sc;
    ss[NF + t] = beta[t] - mean * sc;
}

// -------- apply BN + dinv pre-scale: f32 y -> bf16 x (feeds next hop chain) -------
__global__ void k_apply_h(const float4* __restrict__ y, const float* __restrict__ ss,
                          const float* __restrict__ dinv, ushort4* __restrict__ xh) {
    int idx = blockIdx.x * 256 + threadIdx.x;          // float4 index
    if (idx >= NN * (NF / 4)) return;
    int f = (idx & 63) * 4;
    float di = dinv[idx >> 6];
    float4 v = y[idx];
    ushort4 o;
    o.x = f2bf((v.x * ss[f]     + ss[NF + f])     * di);
    o.y = f2bf((v.y * ss[f + 1] + ss[NF + f + 1]) * di);
    o.z = f2bf((v.z * ss[f + 2] + ss[NF + f + 2]) * di);
    o.w = f2bf((v.w * ss[f + 3] + ss[NF + f + 3]) * di);
    xh[idx] = o;
}

// ---------------- apply BN: f32 y -> f32 output ----------------
__global__ void k_apply_out(const float4* __restrict__ y, const float* __restrict__ ss,
                            float4* __restrict__ out) {
    int idx = blockIdx.x * 256 + threadIdx.x;          // float4 index
    if (idx >= NN * (NF / 4)) return;
    int f = (idx & 63) * 4;
    float4 v = y[idx];
    float4 o;
    o.x = v.x * ss[f]     + ss[NF + f];
    o.y = v.y * ss[f + 1] + ss[NF + f + 1];
    o.z = v.z * ss[f + 2] + ss[NF + f + 2];
    o.w = v.w * ss[f + 3] + ss[NF + f + 3];
    out[idx] = o;
}

extern "C" void kernel_launch(void* const* d_in, const int* in_sizes, int n_in,
                              void* d_out, int out_size, void* d_ws, size_t ws_size,
                              hipStream_t stream) {
    const float* cell  = (const float*)d_in[0];
    const float* sub   = (const float*)d_in[1];
    const int*   ei    = (const int*)  d_in[2];
    const float* ew    = (const float*)d_in[3];
    const float* W1    = (const float*)d_in[4];
    const float* bias1 = (const float*)d_in[5];
    const float* W2    = (const float*)d_in[6];
    const float* bias2 = (const float*)d_in[7];
    const float* pw    = (const float*)d_in[8];
    const float* gamma = (const float*)d_in[9];
    const float* beta  = (const float*)d_in[10];
    float* out = (float*)d_out;        // reference output dtype is float32
    const int E = in_sizes[3];         // 960000 directed edges

    char* ws = (char*)d_ws;
    size_t off = 0;
    auto alloc = [&](size_t bytes) -> void* {
        void* p = ws + off;
        off = (off + bytes + 255) & ~((size_t)255);
        return p;
    };
    ushort*   xh0  = (ushort*)  alloc((size_t)NN * NF * 2);     // bf16 x ping
    ushort*   xh1  = (ushort*)  alloc((size_t)NN * NF * 2);     // bf16 x pong
    ushort*   xht  = (ushort*)  alloc((size_t)NN * NF * 2);     // bf16 x hop-tmp
    float*    yf   = (float*)   alloc((size_t)NN * NF * 4);     // f32 prelu'd gemm out
    ushort*   W1h  = (ushort*)  alloc((size_t)NF * NF * 2);
    ushort*   W2h  = (ushort*)  alloc((size_t)NF * NF * 2);
    unsigned* bkt  = (unsigned*)alloc((size_t)NN * CAP * 4);    // 9.6 MB edge buckets
    int*      fill = (int*)     alloc((size_t)NN * 4);
    float*    s1   = (float*)   alloc((size_t)NN * 4);          // dinv^2
    float*    s2   = (float*)   alloc((size_t)NN * 4);          // dinv
    float*    sums = (float*)   alloc((size_t)2 * NF * 4);
    float*    ss   = (float*)   alloc((size_t)2 * NF * 4);

    const int gN  = (NN + 255) / 256;             // 118
    const int gE  = (E + 255) / 256;
    const int gV4 = (NN * NF / 4 + 255) / 256;    // 7500
    const int gW4 = (NF * NF / 4 + 255) / 256;    // 64
    const int gP  = NN / 4;                       // 7500 blocks, 1 wave/node, 1 chunk
    const int gG  = (NN / 16 + 3) / 4;            // 469 blocks x 4 waves

    k_init<<<gN, 256, 0, stream>>>(fill, sums);
    k_cvtw<<<gW4, 256, 0, stream>>>((const float4*)W1, (ushort4*)W1h);
    k_cvtw<<<gW4, 256, 0, stream>>>((const float4*)W2, (ushort4*)W2h);
    k_scatter<<<gE, 256, 0, stream>>>(ei, ew, fill, bkt, E);
    k_deg<<<gN, 256, 0, stream>>>(bkt, fill, s1, s2);
    k_concat_h<<<gV4, 256, 0, stream>>>((const float4*)cell, (const float4*)sub, s2, (ushort4*)xh0);

    // ---------------- layer 1: 3 hops x 4 feature chunks (hop-major) ----------------
    for (int c = 0; c < 4; c++)
        k_prop_c<<<gP, 256, 0, stream>>>(xh0, xh1, fill, bkt, s1, c);
    for (int c = 0; c < 4; c++)
        k_prop_c<<<gP, 256, 0, stream>>>(xh1, xht, fill, bkt, s1, c);
    for (int c = 0; c < 4; c++)
        k_prop_c<<<gP, 256, 0, stream>>>(xht, xh1, fill, bkt, s2, c);
    k_gemm_fused<<<gG, 256, 0, stream>>>((const short*)xh1, (const short*)W1h, bias1, pw, yf, sums);
    k_finalize<<<1, 256, 0, stream>>>(sums, gamma, beta, ss);
    k_apply_h<<<gV4, 256, 0, stream>>>((const float4*)yf, ss, s2, (ushort4*)xh0);
    k_zero_stats<<<1, 512, 0, stream>>>(sums);

    // ---------------- layer 2 ----------------
    for (int c = 0; c < 4; c++)
        k_prop_c<<<gP, 256, 0, stream>>>(xh0, xh1, fill, bkt, s1, c);
    for (int c = 0; c < 4; c++)
        k_prop_c<<<gP, 256, 0, stream>>>(xh1, xht, fill, bkt, s1, c);
    for (int c = 0; c < 4; c++)
        k_prop_c<<<gP, 256, 0, stream>>>(xht, xh1, fill, bkt, s2, c);
    k_gemm_fused<<<gG, 256, 0, stream>>>((const short*)xh1, (const short*)W2h, bias2, pw, yf, sums);
    k_finalize<<<1, 256, 0, stream>>>(sums, gamma, beta, ss);
    k_apply_out<<<gV4, 256, 0, stream>>>((const float4*)yf, ss, (float4*)out);
}

// Round 9
// 624.183 us; speedup vs baseline: 1.2281x; 1.2281x over previous
//
#include <hip/hip_runtime.h>
#include <hip/hip_bf16.h>

constexpr int NN    = 30000;   // total nodes
constexpr int NCELL = 66;
constexpr int NF    = 256;     // features
constexpr int CAP   = 80;      // bucket capacity per col (in-deg mean 32, P(>80)~1e-8)
constexpr float EPS = 1e-5f;

using bf16x8 = __attribute__((ext_vector_type(8))) short;   // 8 bf16 = 4 VGPRs
using f32x4  = __attribute__((ext_vector_type(4))) float;
using f32x2  = __attribute__((ext_vector_type(2))) float;

__device__ __forceinline__ unsigned short f2bf(float f) {
    __hip_bfloat16 h = __float2bfloat16(f);   // RNE
    return *reinterpret_cast<unsigned short*>(&h);
}
// accumulate 8 bf16 features packed in a float4 (bit halves) into 4x f32x2 (pk_fma)
__device__ __forceinline__ void acc8v(f32x2* acc, float4 u, float w) {
    unsigned a = __float_as_uint(u.x), b = __float_as_uint(u.y);
    unsigned c = __float_as_uint(u.z), d = __float_as_uint(u.w);
    f32x2 wv; wv[0] = w; wv[1] = w;
    f32x2 e0; e0[0] = __uint_as_float(a << 16); e0[1] = __uint_as_float(a & 0xffff0000u);
    f32x2 e1; e1[0] = __uint_as_float(b << 16); e1[1] = __uint_as_float(b & 0xffff0000u);
    f32x2 e2; e2[0] = __uint_as_float(c << 16); e2[1] = __uint_as_float(c & 0xffff0000u);
    f32x2 e3; e3[0] = __uint_as_float(d << 16); e3[1] = __uint_as_float(d & 0xffff0000u);
    acc[0] += wv * e0;
    acc[1] += wv * e1;
    acc[2] += wv * e2;
    acc[3] += wv * e3;
}
// scalar variant for epilogue self-loop add
__device__ __forceinline__ void acc8(float* acc, float4 u, float w) {
    unsigned a = __float_as_uint(u.x), b = __float_as_uint(u.y);
    unsigned c = __float_as_uint(u.z), d = __float_as_uint(u.w);
    acc[0] += w * __uint_as_float(a << 16);
    acc[1] += w * __uint_as_float(a & 0xffff0000u);
    acc[2] += w * __uint_as_float(b << 16);
    acc[3] += w * __uint_as_float(b & 0xffff0000u);
    acc[4] += w * __uint_as_float(c << 16);
    acc[5] += w * __uint_as_float(c & 0xffff0000u);
    acc[6] += w * __uint_as_float(d << 16);
    acc[7] += w * __uint_as_float(d & 0xffff0000u);
}
// packed edge meta: low 16 = src row, high 16 = ew * 2^16 (truncated). CACHED load.
__device__ __forceinline__ void edge_meta(const unsigned* p, int& r, float& w) {
    unsigned v = *p;
    r = (int)(v & 0xffffu);
    w = (float)(v >> 16) * (1.0f / 65536.0f);
}
// recompute BN scale/shift for one col from raw sums (deterministic, ~10 ops)
__device__ __forceinline__ void bn_ss(const float* sums, const float* gamma,
                                      const float* beta, int col, float& sc, float& sh) {
    float mean = sums[col] * (1.0f / (float)NN);
    float var  = sums[NF + col] * (1.0f / (float)NN) - mean * mean;
    if (var < 0.f) var = 0.f;
    float istd = rsqrtf(var + EPS);
    sc = gamma[col] * istd;
    sh = beta[col] - mean * sc;
}

// ------- setup: fill/sums = 0 (blocks 0..117), cvt W1 (118..181), W2 (182..245) ---
__global__ void k_setup(int* fill, float* sums,
                        const float4* __restrict__ W1, ushort4* __restrict__ W1h,
                        const float4* __restrict__ W2, ushort4* __restrict__ W2h) {
    int b = blockIdx.x;
    if (b < 118) {
        int i = b * 256 + threadIdx.x;
        if (i < NN) fill[i] = 0;
        if (i < 2 * NF) sums[i] = 0.0f;
    } else {
        const float4* src = (b < 182) ? W1 : W2;
        ushort4* dst      = (b < 182) ? W1h : W2h;
        int idx = (b - ((b < 182) ? 118 : 182)) * 256 + threadIdx.x;
        if (idx < NF * NF / 4) {
            float4 v = src[idx];
            ushort4 o;
            o.x = f2bf(v.x); o.y = f2bf(v.y); o.z = f2bf(v.z); o.w = f2bf(v.w);
            dst[idx] = o;
        }
    }
}

__global__ void k_zero_stats(float* sums) {
    int i = threadIdx.x;
    if (i < 2 * NF) sums[i] = 0.0f;
}

// ------ scatter, col-range partitioned: block = (edge-slice, range r=bid&7) -------
// Range r owns cols [r*3750,(r+1)*3750) -> each bucket line written by blocks of one
// range; with blockIdx%8 -> XCD round-robin those share an L2 -> lines fill in-cache
// and write back whole (R8 differential evidence: ~35-40us vs 77). CACHED stores.
// col read 8x (L3-resident); row/ew only under the range test.
constexpr int SLICE = 2048;
__global__ __launch_bounds__(256) void k_scatter8(const int* __restrict__ ei,
                                                  const float* __restrict__ ew,
                                                  int* fill, unsigned* __restrict__ bkt,
                                                  int E) {
    int r  = blockIdx.x & 7;
    int s  = blockIdx.x >> 3;
    int lo = r * (NN / 8);
    int hi = lo + (NN / 8);
    int e0 = s * SLICE;
    int e1 = e0 + SLICE; if (e1 > E) e1 = E;
    for (int e = e0 + threadIdx.x; e < e1; e += 256) {
        int col = ei[E + e];
        if (col >= lo && col < hi) {
            int row  = ei[e];
            float wv = ew[e];
            unsigned q = (unsigned)(wv * 65536.0f);   // trunc; ew<1 => q<=65535
            int pos = atomicAdd(&fill[col], 1);
            bkt[(size_t)col * CAP + pos] = ((unsigned)row) | (q << 16);
        }
    }
}

// ------- per-col degree from bucket (exact int sum of ewq), emit scales -----------
// s1 = dinv^2 (hops 1-2 row scale = D^-1), s2 = dinv (hop-3 scale & input pre-scale)
__global__ void k_deg(const unsigned* __restrict__ bkt, const int* __restrict__ fill,
                      float* __restrict__ s1, float* __restrict__ s2) {
    int i = blockIdx.x * 256 + threadIdx.x;
    if (i >= NN) return;
    int cnt = fill[i];
    unsigned sq = 0;
    const unsigned* p = bkt + (size_t)i * CAP;
    for (int e = 0; e < cnt; e++) sq += (p[e] >> 16);
    float deg = 1.0f + (float)sq * (1.0f / 65536.0f);
    float di = rsqrtf(deg);
    s2[i] = di;
    s1[i] = di * di;
}

// ---------------- concat (cell ++ sub), pre-scale by dinv, f32 -> bf16 ------------
__global__ void k_concat_h(const float4* __restrict__ cell, const float4* __restrict__ sub,
                           const float* __restrict__ dinv, ushort4* __restrict__ xh) {
    int idx = blockIdx.x * 256 + threadIdx.x;          // float4 index
    if (idx >= NN * (NF / 4)) return;
    const int CELL4 = NCELL * (NF / 4);
    float4 v = (idx < CELL4) ? cell[idx] : sub[idx - CELL4];
    float di = dinv[idx >> 6];
    ushort4 o;
    o.x = f2bf(v.x * di); o.y = f2bf(v.y * di);
    o.z = f2bf(v.z * di); o.w = f2bf(v.w * di);
    xh[idx] = o;
}

// ------------- one hop: t = (A+I) x, then row-scale; bf16 in/out, f32 accum --------
// R5-verified form (654us, passed): 1 wave/node, 32 lanes x 16B span the row,
// halves do even/odd edges, software-pipelined metas, f32x2 pk_fma accum.
// Plain cached stores (nt/cached mixing caused R8's replay divergence).
__global__ __launch_bounds__(256) void k_prop(const ushort* __restrict__ xin,
                                              ushort* __restrict__ xout,
                                              const int* __restrict__ fill,
                                              const unsigned* __restrict__ bkt,
                                              const float* __restrict__ scale) {
    int n = blockIdx.x * 4 + (threadIdx.x >> 6);
    int lane = threadIdx.x & 63;
    int half = lane >> 5;              // 0: even edges, 1: odd edges
    int fb = lane & 31;                // features fb*8 .. fb*8+7
    const float4* xrow = (const float4*)xin;    // row r = x4[r*32 + fb]
    const unsigned* base = bkt + (size_t)n * CAP;
    int cnt = fill[n];
    float4 uself = xrow[n * 32 + fb];  // early: self-loop row
    float sc = scale[n];               // early: row scale
    f32x2 acc[4];
    #pragma unroll
    for (int i = 0; i < 4; i++) { acc[i][0] = 0.f; acc[i][1] = 0.f; }
    int steps = cnt >> 1;
    int it = 0;
    int e = half;
    if (8 <= steps) {
        unsigned m[8];
        #pragma unroll
        for (int j = 0; j < 8; j++) m[j] = base[e + 2 * j];
        for (;;) {
            int   r[8];
            float w[8];
            #pragma unroll
            for (int j = 0; j < 8; j++) {
                r[j] = (int)(m[j] & 0xffffu);
                w[j] = (float)(m[j] >> 16) * (1.0f / 65536.0f);
            }
            float4 u[8];
            #pragma unroll
            for (int j = 0; j < 8; j++) u[j] = xrow[r[j] * 32 + fb];
            it += 8; e += 16;
            bool more = (it + 8 <= steps);
            if (more) {
                #pragma unroll
                for (int j = 0; j < 8; j++) m[j] = base[e + 2 * j];  // prefetch next batch
            }
            #pragma unroll
            for (int j = 0; j < 8; j++) acc8v(acc, u[j], w[j]);
            if (!more) break;
        }
    }
    for (; it + 4 <= steps; it += 4, e += 8) {
        int r0, r1, r2, r3; float w0, w1, w2, w3;
        edge_meta(base + e,     r0, w0);
        edge_meta(base + e + 2, r1, w1);
        edge_meta(base + e + 4, r2, w2);
        edge_meta(base + e + 6, r3, w3);
        float4 u0 = xrow[r0 * 32 + fb];
        float4 u1 = xrow[r1 * 32 + fb];
        float4 u2 = xrow[r2 * 32 + fb];
        float4 u3 = xrow[r3 * 32 + fb];
        acc8v(acc, u0, w0); acc8v(acc, u1, w1); acc8v(acc, u2, w2); acc8v(acc, u3, w3);
    }
    for (; it < steps; ++it, e += 2) {
        int r0; float w0;
        edge_meta(base + e, r0, w0);
        float4 u0 = xrow[r0 * 32 + fb];
        acc8v(acc, u0, w0);
    }
    if ((cnt & 1) && half == 0) {          // odd remainder edge
        int r0; float w0;
        edge_meta(base + cnt - 1, r0, w0);
        float4 u0 = xrow[r0 * 32 + fb];
        acc8v(acc, u0, w0);
    }
    float accs[8];
    #pragma unroll
    for (int i = 0; i < 4; i++) { accs[2 * i] = acc[i][0]; accs[2 * i + 1] = acc[i][1]; }
    #pragma unroll
    for (int i = 0; i < 8; i++) accs[i] += __shfl_xor(accs[i], 32);
    if (half == 0) {
        acc8(accs, uself, 1.0f);           // self loop, raw weight 1
        #pragma unroll
        for (int i = 0; i < 8; i++) accs[i] *= sc;
        unsigned p0 = ((unsigned)f2bf(accs[1]) << 16) | f2bf(accs[0]);
        unsigned p1 = ((unsigned)f2bf(accs[3]) << 16) | f2bf(accs[2]);
        unsigned p2 = ((unsigned)f2bf(accs[5]) << 16) | f2bf(accs[4]);
        unsigned p3 = ((unsigned)f2bf(accs[7]) << 16) | f2bf(accs[6]);
        float4 o;
        o.x = __uint_as_float(p0); o.y = __uint_as_float(p1);
        o.z = __uint_as_float(p2); o.w = __uint_as_float(p3);
        ((float4*)xout)[n * 32 + fb] = o;
    }
}

// ------- y[m][o] = PReLU(bias[o] + sum_k A[m][k] W[o][k]) -> f32, + BN stats ------
// r9-verified: wave = 16 rows x full 256 cols (acc[16]); stats via LDS block-reduce
// (4 waves) -> 512 atomics/block. Invalid pad wave guarded (no early return).
__global__ __launch_bounds__(256) void k_gemm_fused(const short* __restrict__ A,  // NN x 256 bf16
                                                    const short* __restrict__ B,  // 256 x 256 bf16 (W)
                                                    const float* __restrict__ bias,
                                                    const float* __restrict__ pw,
                                                    float* __restrict__ y,        // NN x 256 f32
                                                    float* __restrict__ sums) {
    constexpr int RT = NN / 16;        // 1875 row tiles
    int w    = threadIdx.x >> 6;       // wave in block
    int lane = threadIdx.x & 63;
    int rt   = blockIdx.x * 4 + w;     // 4 row tiles per block
    int ml   = lane & 15;              // row in tile (A) / col in 16-tile (B, D)
    int q    = lane >> 4;              // quad: A/B k = q*8+j, D row = q*4+r
    bool valid = rt < RT;
    __shared__ float red[2][4][NF];    // [s|s2][wave][col] = 8 KB
    f32x4 acc[16];
    #pragma unroll
    for (int i = 0; i < 16; i++) acc[i] = (f32x4){0.f, 0.f, 0.f, 0.f};
    if (valid) {
        const short* arow = A + (rt * 16 + ml) * NF + q * 8;
        #pragma unroll
        for (int ks = 0; ks < 8; ks++) {
            bf16x8 a = *(const bf16x8*)(arow + ks * 32);
            #pragma unroll
            for (int nt = 0; nt < 16; nt++) {
                bf16x8 b = *(const bf16x8*)(B + (nt * 16 + ml) * NF + ks * 32 + q * 8);
                acc[nt] = __builtin_amdgcn_mfma_f32_16x16x32_bf16(a, b, acc[nt], 0, 0, 0);
            }
        }
    }
    #pragma unroll
    for (int nt = 0; nt < 16; nt++) {
        int col = nt * 16 + ml;
        float s = 0.f, s2 = 0.f;
        if (valid) {
            float bb = bias[col];
            float pc = pw[col];
            #pragma unroll
            for (int r = 0; r < 4; r++) {
                float v = acc[nt][r] + bb;
                v = (v >= 0.f) ? v : pc * v;
                s += v; s2 += v * v;
                y[(rt * 16 + q * 4 + r) * NF + col] = v;
            }
        }
        s  += __shfl_xor(s, 16);  s  += __shfl_xor(s, 32);
        s2 += __shfl_xor(s2, 16); s2 += __shfl_xor(s2, 32);
        if (lane < 16) { red[0][w][col] = s; red[1][w][col] = s2; }
    }
    __syncthreads();
    int t = threadIdx.x;               // t = col, all 256 threads
    float v0 = red[0][0][t] + red[0][1][t] + red[0][2][t] + red[0][3][t];
    float v1 = red[1][0][t] + red[1][1][t] + red[1][2][t] + red[1][3][t];
    atomicAdd(&sums[t], v0);
    atomicAdd(&sums[NF + t], v1);
}

// -- apply BN (scale/shift recomputed per-thread from sums) + dinv, f32 y -> bf16 x --
__global__ void k_apply_h(const float4* __restrict__ y, const float* __restrict__ sums,
                          const float* __restrict__ gamma, const float* __restrict__ beta,
                          const float* __restrict__ dinv, ushort4* __restrict__ xh) {
    int idx = blockIdx.x * 256 + threadIdx.x;          // float4 index
    if (idx >= NN * (NF / 4)) return;
    int f = (idx & 63) * 4;
    float sc0, sh0, sc1, sh1, sc2, sh2, sc3, sh3;
    bn_ss(sums, gamma, beta, f,     sc0, sh0);
    bn_ss(sums, gamma, beta, f + 1, sc1, sh1);
    bn_ss(sums, gamma, beta, f + 2, sc2, sh2);
    bn_ss(sums, gamma, beta, f + 3, sc3, sh3);
    float di = dinv[idx >> 6];
    float4 v = y[idx];
    ushort4 o;
    o.x = f2bf((v.x * sc0 + sh0) * di);
    o.y = f2bf((v.y * sc1 + sh1) * di);
    o.z = f2bf((v.z * sc2 + sh2) * di);
    o.w = f2bf((v.w * sc3 + sh3) * di);
    xh[idx] = o;
}

// ---------------- apply BN (per-thread scale/shift): f32 y -> f32 output ----------
__global__ void k_apply_out(const float4* __restrict__ y, const float* __restrict__ sums,
                            const float* __restrict__ gamma, const float* __restrict__ beta,
                            float4* __restrict__ out) {
    int idx = blockIdx.x * 256 + threadIdx.x;          // float4 index
    if (idx >= NN * (NF / 4)) return;
    int f = (idx & 63) * 4;
    float sc0, sh0, sc1, sh1, sc2, sh2, sc3, sh3;
    bn_ss(sums, gamma, beta, f,     sc0, sh0);
    bn_ss(sums, gamma, beta, f + 1, sc1, sh1);
    bn_ss(sums, gamma, beta, f + 2, sc2, sh2);
    bn_ss(sums, gamma, beta, f + 3, sc3, sh3);
    float4 v = y[idx];
    float4 o;
    o.x = v.x * sc0 + sh0;
    o.y = v.y * sc1 + sh1;
    o.z = v.z * sc2 + sh2;
    o.w = v.w * sc3 + sh3;
    out[idx] = o;
}

extern "C" void kernel_launch(void* const* d_in, const int* in_sizes, int n_in,
                              void* d_out, int out_size, void* d_ws, size_t ws_size,
                              hipStream_t stream) {
    const float* cell  = (const float*)d_in[0];
    const float* sub   = (const float*)d_in[1];
    const int*   ei    = (const int*)  d_in[2];
    const float* ew    = (const float*)d_in[3];
    const float* W1    = (const float*)d_in[4];
    const float* bias1 = (const float*)d_in[5];
    const float* W2    = (const float*)d_in[6];
    const float* bias2 = (const float*)d_in[7];
    const float* pw    = (const float*)d_in[8];
    const float* gamma = (const float*)d_in[9];
    const float* beta  = (const float*)d_in[10];
    float* out = (float*)d_out;        // reference output dtype is float32
    const int E = in_sizes[3];         // 960000 directed edges

    char* ws = (char*)d_ws;
    size_t off = 0;
    auto alloc = [&](size_t bytes) -> void* {
        void* p = ws + off;
        off = (off + bytes + 255) & ~((size_t)255);
        return p;
    };
    ushort*   xh0  = (ushort*)  alloc((size_t)NN * NF * 2);     // bf16 x ping
    ushort*   xh1  = (ushort*)  alloc((size_t)NN * NF * 2);     // bf16 x pong
    float*    yf   = (float*)   alloc((size_t)NN * NF * 4);     // f32 prelu'd gemm out
    ushort*   W1h  = (ushort*)  alloc((size_t)NF * NF * 2);
    ushort*   W2h  = (ushort*)  alloc((size_t)NF * NF * 2);
    unsigned* bkt  = (unsigned*)alloc((size_t)NN * CAP * 4);    // 9.6 MB edge buckets
    int*      fill = (int*)     alloc((size_t)NN * 4);
    float*    s1   = (float*)   alloc((size_t)NN * 4);          // dinv^2
    float*    s2   = (float*)   alloc((size_t)NN * 4);          // dinv
    float*    sums = (float*)   alloc((size_t)2 * NF * 4);

    const int gN  = (NN + 255) / 256;             // 118
    const int gSU = 118 + 64 + 64;                // 246: init + cvtw1 + cvtw2
    const int gS8 = ((E + SLICE - 1) / SLICE) * 8;// (slice, range) pairs
    const int gV4 = (NN * NF / 4 + 255) / 256;    // 7500
    const int gP  = NN / 4;                       // 7500 blocks, 1 wave/node
    const int gG  = (NN / 16 + 3) / 4;            // 469 blocks x 4 waves

    k_setup<<<gSU, 256, 0, stream>>>(fill, sums, (const float4*)W1, (ushort4*)W1h,
                                     (const float4*)W2, (ushort4*)W2h);
    k_scatter8<<<gS8, 256, 0, stream>>>(ei, ew, fill, bkt, E);
    k_deg<<<gN, 256, 0, stream>>>(bkt, fill, s1, s2);
    k_concat_h<<<gV4, 256, 0, stream>>>((const float4*)cell, (const float4*)sub, s2, (ushort4*)xh0);

    // ---------------- layer 1 ----------------
    k_prop<<<gP, 256, 0, stream>>>(xh0, xh1, fill, bkt, s1);
    k_prop<<<gP, 256, 0, stream>>>(xh1, xh0, fill, bkt, s1);
    k_prop<<<gP, 256, 0, stream>>>(xh0, xh1, fill, bkt, s2);
    k_gemm_fused<<<gG, 256, 0, stream>>>((const short*)xh1, (const short*)W1h, bias1, pw, yf, sums);
    k_apply_h<<<gV4, 256, 0, stream>>>((const float4*)yf, sums, gamma, beta, s2, (ushort4*)xh0);
    k_zero_stats<<<1, 512, 0, stream>>>(sums);

    // ---------------- layer 2 ----------------
    k_prop<<<gP, 256, 0, stream>>>(xh0, xh1, fill, bkt, s1);
    k_prop<<<gP, 256, 0, stream>>>(xh1, xh0, fill, bkt, s1);
    k_prop<<<gP, 256, 0, stream>>>(xh0, xh1, fill, bkt, s2);
    k_gemm_fused<<<gG, 256, 0, stream>>>((const short*)xh1, (const short*)W2h, bias2, pw, yf, sums);
    k_apply_out<<<gV4, 256, 0, stream>>>((const float4*)yf, sums, gamma, beta, (float4*)out);
}

// Round 11
// 621.394 us; speedup vs baseline: 1.2336x; 1.0045x over previous
//
#include <hip/hip_runtime.h>
#include <hip/hip_bf16.h>

constexpr int NN    = 30000;   // total nodes
constexpr int NCELL = 66;
constexpr int NF    = 256;     // features
constexpr int CAP   = 80;      // bucket capacity per col (in-deg mean 32, P(>80)~1e-8)
constexpr float EPS = 1e-5f;

using bf16x8 = __attribute__((ext_vector_type(8))) short;   // 8 bf16 = 4 VGPRs
using f32x4  = __attribute__((ext_vector_type(4))) float;
using f32x2  = __attribute__((ext_vector_type(2))) float;

__device__ __forceinline__ unsigned short f2bf(float f) {
    __hip_bfloat16 h = __float2bfloat16(f);   // RNE
    return *reinterpret_cast<unsigned short*>(&h);
}
__device__ __forceinline__ float bf2f(unsigned short u) {
    return __uint_as_float(((unsigned)u) << 16);
}
// accumulate 8 bf16 features packed in a float4 (bit halves) into 4x f32x2 (pk_fma)
__device__ __forceinline__ void acc8v(f32x2* acc, float4 u, float w) {
    unsigned a = __float_as_uint(u.x), b = __float_as_uint(u.y);
    unsigned c = __float_as_uint(u.z), d = __float_as_uint(u.w);
    f32x2 wv; wv[0] = w; wv[1] = w;
    f32x2 e0; e0[0] = __uint_as_float(a << 16); e0[1] = __uint_as_float(a & 0xffff0000u);
    f32x2 e1; e1[0] = __uint_as_float(b << 16); e1[1] = __uint_as_float(b & 0xffff0000u);
    f32x2 e2; e2[0] = __uint_as_float(c << 16); e2[1] = __uint_as_float(c & 0xffff0000u);
    f32x2 e3; e3[0] = __uint_as_float(d << 16); e3[1] = __uint_as_float(d & 0xffff0000u);
    acc[0] += wv * e0;
    acc[1] += wv * e1;
    acc[2] += wv * e2;
    acc[3] += wv * e3;
}
// scalar variant for epilogue self-loop add
__device__ __forceinline__ void acc8(float* acc, float4 u, float w) {
    unsigned a = __float_as_uint(u.x), b = __float_as_uint(u.y);
    unsigned c = __float_as_uint(u.z), d = __float_as_uint(u.w);
    acc[0] += w * __uint_as_float(a << 16);
    acc[1] += w * __uint_as_float(a & 0xffff0000u);
    acc[2] += w * __uint_as_float(b << 16);
    acc[3] += w * __uint_as_float(b & 0xffff0000u);
    acc[4] += w * __uint_as_float(c << 16);
    acc[5] += w * __uint_as_float(c & 0xffff0000u);
    acc[6] += w * __uint_as_float(d << 16);
    acc[7] += w * __uint_as_float(d & 0xffff0000u);
}
// recompute BN scale/shift for one col from raw sums (deterministic, ~10 ops)
__device__ __forceinline__ void bn_ss(const float* sums, const float* gamma,
                                      const float* beta, int col, float& sc, float& sh) {
    float mean = sums[col] * (1.0f / (float)NN);
    float var  = sums[NF + col] * (1.0f / (float)NN) - mean * mean;
    if (var < 0.f) var = 0.f;
    float istd = rsqrtf(var + EPS);
    sc = gamma[col] * istd;
    sh = beta[col] - mean * sc;
}

// ------- setup: fill/sums = 0 (blocks 0..117), cvt W1 (118..181), W2 (182..245) ---
__global__ void k_setup(int* fill, float* sums,
                        const float4* __restrict__ W1, ushort4* __restrict__ W1h,
                        const float4* __restrict__ W2, ushort4* __restrict__ W2h) {
    int b = blockIdx.x;
    if (b < 118) {
        int i = b * 256 + threadIdx.x;
        if (i < NN) fill[i] = 0;
        if (i < 2 * NF) sums[i] = 0.0f;
    } else {
        const float4* src = (b < 182) ? W1 : W2;
        ushort4* dst      = (b < 182) ? W1h : W2h;
        int idx = (b - ((b < 182) ? 118 : 182)) * 256 + threadIdx.x;
        if (idx < NF * NF / 4) {
            float4 v = src[idx];
            ushort4 o;
            o.x = f2bf(v.x); o.y = f2bf(v.y); o.z = f2bf(v.z); o.w = f2bf(v.w);
            dst[idx] = o;
        }
    }
}

__global__ void k_zero_stats(float* sums) {
    int i = threadIdx.x;
    if (i < 2 * NF) sums[i] = 0.0f;
}

// ------ scatter, col-range partitioned: block = (edge-slice, range r=bid&7) -------
// Range r owns cols [r*3750,(r+1)*3750) -> each bucket line written by blocks of one
// range; with blockIdx%8 -> XCD round-robin those share an L2 -> lines fill in-cache
// and write back whole (R8->R9 differential: part of the 654->624 win). CACHED
// stores. col read 8x (L3-resident); row/ew only under the range test.
constexpr int SLICE = 2048;
__global__ __launch_bounds__(256) void k_scatter8(const int* __restrict__ ei,
                                                  const float* __restrict__ ew,
                                                  int* fill, unsigned* __restrict__ bkt,
                                                  int E) {
    int r  = blockIdx.x & 7;
    int s  = blockIdx.x >> 3;
    int lo = r * (NN / 8);
    int hi = lo + (NN / 8);
    int e0 = s * SLICE;
    int e1 = e0 + SLICE; if (e1 > E) e1 = E;
    for (int e = e0 + threadIdx.x; e < e1; e += 256) {
        int col = ei[E + e];
        if (col >= lo && col < hi) {
            int row  = ei[e];
            float wv = ew[e];
            unsigned q = (unsigned)(wv * 65536.0f);   // trunc; ew<1 => q<=65535
            int pos = atomicAdd(&fill[col], 1);
            bkt[(size_t)col * CAP + pos] = ((unsigned)row) | (q << 16);
        }
    }
}

// --- fused deg + concat: 8 nodes/block; 32-lane group: degree-reduce -> prescale ---
// group g owns node n = bid*8+g: sum ewq over bucket (32-lane strided + shfl tree),
// emit s1 = dinv^2, s2 = dinv; then the same 32 lanes convert/prescale node n's
// 256-feat row (64 float4, 2 per lane) using the just-computed dinv (no round-trip).
__global__ __launch_bounds__(256) void k_degcat(const unsigned* __restrict__ bkt,
                                                const int* __restrict__ fill,
                                                const float4* __restrict__ cell,
                                                const float4* __restrict__ sub,
                                                float* __restrict__ s1,
                                                float* __restrict__ s2,
                                                ushort4* __restrict__ xh) {
    int g  = threadIdx.x >> 5;          // group 0..7
    int l  = threadIdx.x & 31;          // lane in group
    int n  = blockIdx.x * 8 + g;
    int cnt = fill[n];
    const unsigned* p = bkt + (size_t)n * CAP;
    unsigned sq = 0;
    for (int e = l; e < cnt; e += 32) sq += (p[e] >> 16);
    sq += __shfl_xor((int)sq, 1);
    sq += __shfl_xor((int)sq, 2);
    sq += __shfl_xor((int)sq, 4);
    sq += __shfl_xor((int)sq, 8);
    sq += __shfl_xor((int)sq, 16);
    float deg = 1.0f + (float)sq * (1.0f / 65536.0f);
    float di = rsqrtf(deg);
    if (l == 0) { s2[n] = di; s1[n] = di * di; }
    const int CELL4 = NCELL * (NF / 4);
    #pragma unroll
    for (int k = 0; k < 2; k++) {
        int gidx = n * 64 + l + 32 * k;          // float4 index in [NN][256]
        float4 v = (gidx < CELL4) ? cell[gidx] : sub[gidx - CELL4];
        ushort4 o;
        o.x = f2bf(v.x * di); o.y = f2bf(v.y * di);
        o.z = f2bf(v.z * di); o.w = f2bf(v.w * di);
        xh[gidx] = o;
    }
}

// ------------- one hop: t = (A+I) x, then row-scale; bf16 in/out, f32 accum --------
// R9-verified structure (59us, FETCH 190MB). Delta: metas now NT-hinted — the
// 3.84MB single-use meta stream shouldn't evict x's L2 lines (x is the 62%-hit
// working set; misses are the 3.5TB/s fabric bottleneck).
__global__ __launch_bounds__(256) void k_prop(const ushort* __restrict__ xin,
                                              ushort* __restrict__ xout,
                                              const int* __restrict__ fill,
                                              const unsigned* __restrict__ bkt,
                                              const float* __restrict__ scale) {
    int n = blockIdx.x * 4 + (threadIdx.x >> 6);
    int lane = threadIdx.x & 63;
    int half = lane >> 5;              // 0: even edges, 1: odd edges
    int fb = lane & 31;                // features fb*8 .. fb*8+7
    const float4* xrow = (const float4*)xin;    // row r = x4[r*32 + fb]
    const unsigned* base = bkt + (size_t)n * CAP;
    int cnt = fill[n];
    float4 uself = xrow[n * 32 + fb];  // early: self-loop row
    float sc = scale[n];               // early: row scale
    f32x2 acc[4];
    #pragma unroll
    for (int i = 0; i < 4; i++) { acc[i][0] = 0.f; acc[i][1] = 0.f; }
    int steps = cnt >> 1;
    int it = 0;
    int e = half;
    if (8 <= steps) {
        unsigned m[8];
        #pragma unroll
        for (int j = 0; j < 8; j++) m[j] = __builtin_nontemporal_load(base + e + 2 * j);
        for (;;) {
            int   r[8];
            float w[8];
            #pragma unroll
            for (int j = 0; j < 8; j++) {
                r[j] = (int)(m[j] & 0xffffu);
                w[j] = (float)(m[j] >> 16) * (1.0f / 65536.0f);
            }
            float4 u[8];
            #pragma unroll
            for (int j = 0; j < 8; j++) u[j] = xrow[r[j] * 32 + fb];
            it += 8; e += 16;
            bool more = (it + 8 <= steps);
            if (more) {
                #pragma unroll
                for (int j = 0; j < 8; j++) m[j] = __builtin_nontemporal_load(base + e + 2 * j);
            }
            #pragma unroll
            for (int j = 0; j < 8; j++) acc8v(acc, u[j], w[j]);
            if (!more) break;
        }
    }
    for (; it + 4 <= steps; it += 4, e += 8) {
        unsigned m0 = __builtin_nontemporal_load(base + e);
        unsigned m1 = __builtin_nontemporal_load(base + e + 2);
        unsigned m2 = __builtin_nontemporal_load(base + e + 4);
        unsigned m3 = __builtin_nontemporal_load(base + e + 6);
        int r0 = (int)(m0 & 0xffffu), r1 = (int)(m1 & 0xffffu);
        int r2 = (int)(m2 & 0xffffu), r3 = (int)(m3 & 0xffffu);
        float w0 = (float)(m0 >> 16) * (1.0f / 65536.0f);
        float w1 = (float)(m1 >> 16) * (1.0f / 65536.0f);
        float w2 = (float)(m2 >> 16) * (1.0f / 65536.0f);
        float w3 = (float)(m3 >> 16) * (1.0f / 65536.0f);
        float4 u0 = xrow[r0 * 32 + fb];
        float4 u1 = xrow[r1 * 32 + fb];
        float4 u2 = xrow[r2 * 32 + fb];
        float4 u3 = xrow[r3 * 32 + fb];
        acc8v(acc, u0, w0); acc8v(acc, u1, w1); acc8v(acc, u2, w2); acc8v(acc, u3, w3);
    }
    for (; it < steps; ++it, e += 2) {
        unsigned m0 = __builtin_nontemporal_load(base + e);
        int r0 = (int)(m0 & 0xffffu);
        float w0 = (float)(m0 >> 16) * (1.0f / 65536.0f);
        float4 u0 = xrow[r0 * 32 + fb];
        acc8v(acc, u0, w0);
    }
    if ((cnt & 1) && half == 0) {          // odd remainder edge
        unsigned m0 = __builtin_nontemporal_load(base + cnt - 1);
        int r0 = (int)(m0 & 0xffffu);
        float w0 = (float)(m0 >> 16) * (1.0f / 65536.0f);
        float4 u0 = xrow[r0 * 32 + fb];
        acc8v(acc, u0, w0);
    }
    float accs[8];
    #pragma unroll
    for (int i = 0; i < 4; i++) { accs[2 * i] = acc[i][0]; accs[2 * i + 1] = acc[i][1]; }
    #pragma unroll
    for (int i = 0; i < 8; i++) accs[i] += __shfl_xor(accs[i], 32);
    if (half == 0) {
        acc8(accs, uself, 1.0f);           // self loop, raw weight 1
        #pragma unroll
        for (int i = 0; i < 8; i++) accs[i] *= sc;
        unsigned p0 = ((unsigned)f2bf(accs[1]) << 16) | f2bf(accs[0]);
        unsigned p1 = ((unsigned)f2bf(accs[3]) << 16) | f2bf(accs[2]);
        unsigned p2 = ((unsigned)f2bf(accs[5]) << 16) | f2bf(accs[4]);
        unsigned p3 = ((unsigned)f2bf(accs[7]) << 16) | f2bf(accs[6]);
        float4 o;
        o.x = __uint_as_float(p0); o.y = __uint_as_float(p1);
        o.z = __uint_as_float(p2); o.w = __uint_as_float(p3);
        ((float4*)xout)[n * 32 + fb] = o;
    }
}

// ------- y[m][o] = PReLU(bias[o] + sum_k A[m][k] W[o][k]) -> BF16, + BN stats -----
// Stats (s, s2) accumulate in f32 from pre-rounding values; y stored bf16 (halves
// the y round-trip traffic: 61MB -> 46MB per layer).
__global__ __launch_bounds__(256) void k_gemm_fused(const short* __restrict__ A,  // NN x 256 bf16
                                                    const short* __restrict__ B,  // 256 x 256 bf16 (W)
                                                    const float* __restrict__ bias,
                                                    const float* __restrict__ pw,
                                                    ushort* __restrict__ yh,      // NN x 256 bf16
                                                    float* __restrict__ sums) {
    constexpr int RT = NN / 16;        // 1875 row tiles
    int w    = threadIdx.x >> 6;       // wave in block
    int lane = threadIdx.x & 63;
    int rt   = blockIdx.x * 4 + w;     // 4 row tiles per block
    int ml   = lane & 15;              // row in tile (A) / col in 16-tile (B, D)
    int q    = lane >> 4;              // quad: A/B k = q*8+j, D row = q*4+r
    bool valid = rt < RT;
    __shared__ float red[2][4][NF];    // [s|s2][wave][col] = 8 KB
    f32x4 acc[16];
    #pragma unroll
    for (int i = 0; i < 16; i++) acc[i] = (f32x4){0.f, 0.f, 0.f, 0.f};
    if (valid) {
        const short* arow = A + (rt * 16 + ml) * NF + q * 8;
        #pragma unroll
        for (int ks = 0; ks < 8; ks++) {
            bf16x8 a = *(const bf16x8*)(arow + ks * 32);
            #pragma unroll
            for (int nt = 0; nt < 16; nt++) {
                bf16x8 b = *(const bf16x8*)(B + (nt * 16 + ml) * NF + ks * 32 + q * 8);
                acc[nt] = __builtin_amdgcn_mfma_f32_16x16x32_bf16(a, b, acc[nt], 0, 0, 0);
            }
        }
    }
    #pragma unroll
    for (int nt = 0; nt < 16; nt++) {
        int col = nt * 16 + ml;
        float s = 0.f, s2 = 0.f;
        if (valid) {
            float bb = bias[col];
            float pc = pw[col];
            #pragma unroll
            for (int r = 0; r < 4; r++) {
                float v = acc[nt][r] + bb;
                v = (v >= 0.f) ? v : pc * v;
                s += v; s2 += v * v;
                yh[(rt * 16 + q * 4 + r) * NF + col] = f2bf(v);
            }
        }
        s  += __shfl_xor(s, 16);  s  += __shfl_xor(s, 32);
        s2 += __shfl_xor(s2, 16); s2 += __shfl_xor(s2, 32);
        if (lane < 16) { red[0][w][col] = s; red[1][w][col] = s2; }
    }
    __syncthreads();
    int t = threadIdx.x;               // t = col, all 256 threads
    float v0 = red[0][0][t] + red[0][1][t] + red[0][2][t] + red[0][3][t];
    float v1 = red[1][0][t] + red[1][1][t] + red[1][2][t] + red[1][3][t];
    atomicAdd(&sums[t], v0);
    atomicAdd(&sums[NF + t], v1);
}

// -- apply BN (scale/shift recomputed per-thread from sums) + dinv, bf16 y -> bf16 x --
__global__ void k_apply_h(const ushort4* __restrict__ yh, const float* __restrict__ sums,
                          const float* __restrict__ gamma, const float* __restrict__ beta,
                          const float* __restrict__ dinv, ushort4* __restrict__ xh) {
    int idx = blockIdx.x * 256 + threadIdx.x;          // ushort4 index (4 bf16)
    if (idx >= NN * (NF / 4)) return;
    int f = (idx & 63) * 4;
    float sc0, sh0, sc1, sh1, sc2, sh2, sc3, sh3;
    bn_ss(sums, gamma, beta, f,     sc0, sh0);
    bn_ss(sums, gamma, beta, f + 1, sc1, sh1);
    bn_ss(sums, gamma, beta, f + 2, sc2, sh2);
    bn_ss(sums, gamma, beta, f + 3, sc3, sh3);
    float di = dinv[idx >> 6];
    ushort4 v = yh[idx];
    ushort4 o;
    o.x = f2bf((bf2f(v.x) * sc0 + sh0) * di);
    o.y = f2bf((bf2f(v.y) * sc1 + sh1) * di);
    o.z = f2bf((bf2f(v.z) * sc2 + sh2) * di);
    o.w = f2bf((bf2f(v.w) * sc3 + sh3) * di);
    xh[idx] = o;
}

// -------- apply BN (per-thread scale/shift): bf16 y -> f32 output -----------------
__global__ void k_apply_out(const ushort4* __restrict__ yh, const float* __restrict__ sums,
                            const float* __restrict__ gamma, const float* __restrict__ beta,
                            float4* __restrict__ out) {
    int idx = blockIdx.x * 256 + threadIdx.x;          // ushort4 index (4 bf16)
    if (idx >= NN * (NF / 4)) return;
    int f = (idx & 63) * 4;
    float sc0, sh0, sc1, sh1, sc2, sh2, sc3, sh3;
    bn_ss(sums, gamma, beta, f,     sc0, sh0);
    bn_ss(sums, gamma, beta, f + 1, sc1, sh1);
    bn_ss(sums, gamma, beta, f + 2, sc2, sh2);
    bn_ss(sums, gamma, beta, f + 3, sc3, sh3);
    ushort4 v = yh[idx];
    float4 o;
    o.x = bf2f(v.x) * sc0 + sh0;
    o.y = bf2f(v.y) * sc1 + sh1;
    o.z = bf2f(v.z) * sc2 + sh2;
    o.w = bf2f(v.w) * sc3 + sh3;
    out[idx] = o;
}

extern "C" void kernel_launch(void* const* d_in, const int* in_sizes, int n_in,
                              void* d_out, int out_size, void* d_ws, size_t ws_size,
                              hipStream_t stream) {
    const float* cell  = (const float*)d_in[0];
    const float* sub   = (const float*)d_in[1];
    const int*   ei    = (const int*)  d_in[2];
    const float* ew    = (const float*)d_in[3];
    const float* W1    = (const float*)d_in[4];
    const float* bias1 = (const float*)d_in[5];
    const float* W2    = (const float*)d_in[6];
    const float* bias2 = (const float*)d_in[7];
    const float* pw    = (const float*)d_in[8];
    const float* gamma = (const float*)d_in[9];
    const float* beta  = (const float*)d_in[10];
    float* out = (float*)d_out;        // reference output dtype is float32
    const int E = in_sizes[3];         // 960000 directed edges

    char* ws = (char*)d_ws;
    size_t off = 0;
    auto alloc = [&](size_t bytes) -> void* {
        void* p = ws + off;
        off = (off + bytes + 255) & ~((size_t)255);
        return p;
    };
    ushort*   xh0  = (ushort*)  alloc((size_t)NN * NF * 2);     // bf16 x ping
    ushort*   xh1  = (ushort*)  alloc((size_t)NN * NF * 2);     // bf16 x pong
    ushort*   yh   = (ushort*)  alloc((size_t)NN * NF * 2);     // bf16 prelu'd gemm out
    ushort*   W1h  = (ushort*)  alloc((size_t)NF * NF * 2);
    ushort*   W2h  = (ushort*)  alloc((size_t)NF * NF * 2);
    unsigned* bkt  = (unsigned*)alloc((size_t)NN * CAP * 4);    // 9.6 MB edge buckets
    int*      fill = (int*)     alloc((size_t)NN * 4);
    float*    s1   = (float*)   alloc((size_t)NN * 4);          // dinv^2
    float*    s2   = (float*)   alloc((size_t)NN * 4);          // dinv
    float*    sums = (float*)   alloc((size_t)2 * NF * 4);

    const int gSU = 118 + 64 + 64;                // 246: init + cvtw1 + cvtw2
    const int gS8 = ((E + SLICE - 1) / SLICE) * 8;// (slice, range) pairs
    const int gDC = NN / 8;                       // 3750 blocks, 8 nodes each
    const int gV4 = (NN * NF / 4 + 255) / 256;    // 7500
    const int gP  = NN / 4;                       // 7500 blocks, 1 wave/node
    const int gG  = (NN / 16 + 3) / 4;            // 469 blocks x 4 waves

    k_setup<<<gSU, 256, 0, stream>>>(fill, sums, (const float4*)W1, (ushort4*)W1h,
                                     (const float4*)W2, (ushort4*)W2h);
    k_scatter8<<<gS8, 256, 0, stream>>>(ei, ew, fill, bkt, E);
    k_degcat<<<gDC, 256, 0, stream>>>(bkt, fill, (const float4*)cell, (const float4*)sub,
                                      s1, s2, (ushort4*)xh0);

    // ---------------- layer 1 ----------------
    k_prop<<<gP, 256, 0, stream>>>(xh0, xh1, fill, bkt, s1);
    k_prop<<<gP, 256, 0, stream>>>(xh1, xh0, fill, bkt, s1);
    k_prop<<<gP, 256, 0, stream>>>(xh0, xh1, fill, bkt, s2);
    k_gemm_fused<<<gG, 256, 0, stream>>>((const short*)xh1, (const short*)W1h, bias1, pw, yh, sums);
    k_apply_h<<<gV4, 256, 0, stream>>>((const ushort4*)yh, sums, gamma, beta, s2, (ushort4*)xh0);
    k_zero_stats<<<1, 512, 0, stream>>>(sums);

    // ---------------- layer 2 ----------------
    k_prop<<<gP, 256, 0, stream>>>(xh0, xh1, fill, bkt, s1);
    k_prop<<<gP, 256, 0, stream>>>(xh1, xh0, fill, bkt, s1);
    k_prop<<<gP, 256, 0, stream>>>(xh0, xh1, fill, bkt, s2);
    k_gemm_fused<<<gG, 256, 0, stream>>>((const short*)xh1, (const short*)W2h, bias2, pw, yh, sums);
    k_apply_out<<<gV4, 256, 0, stream>>>((const ushort4*)yh, sums, gamma, beta, (float4*)out);
}

// Round 12
// 608.511 us; speedup vs baseline: 1.2597x; 1.0212x over previous
//
#include <hip/hip_runtime.h>
#include <hip/hip_bf16.h>

constexpr int NN    = 30000;   // total nodes
constexpr int NCELL = 66;
constexpr int NF    = 256;     // features
constexpr int CAP   = 80;      // bucket capacity per col (in-deg mean 32, P(>80)~1e-8)
constexpr float EPS = 1e-5f;

using bf16x8 = __attribute__((ext_vector_type(8))) short;   // 8 bf16 = 4 VGPRs
using f32x4  = __attribute__((ext_vector_type(4))) float;
using f32x2  = __attribute__((ext_vector_type(2))) float;

__device__ __forceinline__ unsigned short f2bf(float f) {
    __hip_bfloat16 h = __float2bfloat16(f);   // RNE
    return *reinterpret_cast<unsigned short*>(&h);
}
__device__ __forceinline__ float bf2f(unsigned short u) {
    return __uint_as_float(((unsigned)u) << 16);
}
// accumulate 8 bf16 features packed in a float4 (bit halves) into 4x f32x2 (pk_fma)
__device__ __forceinline__ void acc8v(f32x2* acc, float4 u, float w) {
    unsigned a = __float_as_uint(u.x), b = __float_as_uint(u.y);
    unsigned c = __float_as_uint(u.z), d = __float_as_uint(u.w);
    f32x2 wv; wv[0] = w; wv[1] = w;
    f32x2 e0; e0[0] = __uint_as_float(a << 16); e0[1] = __uint_as_float(a & 0xffff0000u);
    f32x2 e1; e1[0] = __uint_as_float(b << 16); e1[1] = __uint_as_float(b & 0xffff0000u);
    f32x2 e2; e2[0] = __uint_as_float(c << 16); e2[1] = __uint_as_float(c & 0xffff0000u);
    f32x2 e3; e3[0] = __uint_as_float(d << 16); e3[1] = __uint_as_float(d & 0xffff0000u);
    acc[0] += wv * e0;
    acc[1] += wv * e1;
    acc[2] += wv * e2;
    acc[3] += wv * e3;
}
// scalar variant for epilogue self-loop add
__device__ __forceinline__ void acc8(float* acc, float4 u, float w) {
    unsigned a = __float_as_uint(u.x), b = __float_as_uint(u.y);
    unsigned c = __float_as_uint(u.z), d = __float_as_uint(u.w);
    acc[0] += w * __uint_as_float(a << 16);
    acc[1] += w * __uint_as_float(a & 0xffff0000u);
    acc[2] += w * __uint_as_float(b << 16);
    acc[3] += w * __uint_as_float(b & 0xffff0000u);
    acc[4] += w * __uint_as_float(c << 16);
    acc[5] += w * __uint_as_float(c & 0xffff0000u);
    acc[6] += w * __uint_as_float(d << 16);
    acc[7] += w * __uint_as_float(d & 0xffff0000u);
}
// recompute BN scale/shift for one col from raw sums (deterministic, ~10 ops)
__device__ __forceinline__ void bn_ss(const float* sums, const float* gamma,
                                      const float* beta, int col, float& sc, float& sh) {
    float mean = sums[col] * (1.0f / (float)NN);
    float var  = sums[NF + col] * (1.0f / (float)NN) - mean * mean;
    if (var < 0.f) var = 0.f;
    float istd = rsqrtf(var + EPS);
    sc = gamma[col] * istd;
    sh = beta[col] - mean * sc;
}

// ------- setup: fill/sums = 0 (blocks 0..117), cvt W1 (118..181), W2 (182..245) ---
__global__ void k_setup(int* fill, float* sums,
                        const float4* __restrict__ W1, ushort4* __restrict__ W1h,
                        const float4* __restrict__ W2, ushort4* __restrict__ W2h) {
    int b = blockIdx.x;
    if (b < 118) {
        int i = b * 256 + threadIdx.x;
        if (i < NN) fill[i] = 0;
        if (i < 2 * NF) sums[i] = 0.0f;
    } else {
        const float4* src = (b < 182) ? W1 : W2;
        ushort4* dst      = (b < 182) ? W1h : W2h;
        int idx = (b - ((b < 182) ? 118 : 182)) * 256 + threadIdx.x;
        if (idx < NF * NF / 4) {
            float4 v = src[idx];
            ushort4 o;
            o.x = f2bf(v.x); o.y = f2bf(v.y); o.z = f2bf(v.z); o.w = f2bf(v.w);
            dst[idx] = o;
        }
    }
}

__global__ void k_zero_stats(float* sums) {
    int i = threadIdx.x;
    if (i < 2 * NF) sums[i] = 0.0f;
}

// ------ scatter, col-range partitioned: block = (edge-slice, range r=bid&7) -------
// Range r owns cols [r*3750,(r+1)*3750) -> each bucket line written by blocks of one
// range; with blockIdx%8 -> XCD round-robin those share an L2 -> lines fill in-cache
// and write back whole (R8->R9 differential: part of the 654->624 win). CACHED
// stores. col read 8x (L3-resident); row/ew only under the range test.
constexpr int SLICE = 2048;
__global__ __launch_bounds__(256) void k_scatter8(const int* __restrict__ ei,
                                                  const float* __restrict__ ew,
                                                  int* fill, unsigned* __restrict__ bkt,
                                                  int E) {
    int r  = blockIdx.x & 7;
    int s  = blockIdx.x >> 3;
    int lo = r * (NN / 8);
    int hi = lo + (NN / 8);
    int e0 = s * SLICE;
    int e1 = e0 + SLICE; if (e1 > E) e1 = E;
    for (int e = e0 + threadIdx.x; e < e1; e += 256) {
        int col = ei[E + e];
        if (col >= lo && col < hi) {
            int row  = ei[e];
            float wv = ew[e];
            unsigned q = (unsigned)(wv * 65536.0f);   // trunc; ew<1 => q<=65535
            int pos = atomicAdd(&fill[col], 1);
            bkt[(size_t)col * CAP + pos] = ((unsigned)row) | (q << 16);
        }
    }
}

// --- fused deg + concat: 8 nodes/block; 32-lane group: degree-reduce -> prescale ---
// group g owns node n = bid*8+g: sum ewq over bucket (32-lane strided + shfl tree),
// emit s1 = dinv^2, s2 = dinv; then the same 32 lanes convert/prescale node n's
// 256-feat row (64 float4, 2 per lane) using the just-computed dinv (no round-trip).
__global__ __launch_bounds__(256) void k_degcat(const unsigned* __restrict__ bkt,
                                                const int* __restrict__ fill,
                                                const float4* __restrict__ cell,
                                                const float4* __restrict__ sub,
                                                float* __restrict__ s1,
                                                float* __restrict__ s2,
                                                ushort4* __restrict__ xh) {
    int g  = threadIdx.x >> 5;          // group 0..7
    int l  = threadIdx.x & 31;          // lane in group
    int n  = blockIdx.x * 8 + g;
    int cnt = fill[n];
    const unsigned* p = bkt + (size_t)n * CAP;
    unsigned sq = 0;
    for (int e = l; e < cnt; e += 32) sq += (p[e] >> 16);
    sq += __shfl_xor((int)sq, 1);
    sq += __shfl_xor((int)sq, 2);
    sq += __shfl_xor((int)sq, 4);
    sq += __shfl_xor((int)sq, 8);
    sq += __shfl_xor((int)sq, 16);
    float deg = 1.0f + (float)sq * (1.0f / 65536.0f);
    float di = rsqrtf(deg);
    if (l == 0) { s2[n] = di; s1[n] = di * di; }
    const int CELL4 = NCELL * (NF / 4);
    #pragma unroll
    for (int k = 0; k < 2; k++) {
        int gidx = n * 64 + l + 32 * k;          // float4 index in [NN][256]
        float4 v = (gidx < CELL4) ? cell[gidx] : sub[gidx - CELL4];
        ushort4 o;
        o.x = f2bf(v.x * di); o.y = f2bf(v.y * di);
        o.z = f2bf(v.z * di); o.w = f2bf(v.w * di);
        xh[gidx] = o;
    }
}

// ------------- one hop: t = (A+I) x, then row-scale; bf16 in/out, f32 accum --------
// Deltas vs R11: (1) metas back to CACHED loads (nt was +3MB FETCH, +1.7us — R11
// A/B); (2) uniform PREDICATED 16-deep batches: every half-wave keeps 16 row-loads
// in flight every iteration (OOB edges -> w=0 + harmless row-0 read), replacing the
// 8/4/1-deep remainder ladder. Little's-law: ~9.6KB/CU must be in flight to sustain
// the measured 3.5TB/s fabric rate; the old shallow remainders starved it for
// low-degree nodes.
__global__ __launch_bounds__(256) void k_prop(const ushort* __restrict__ xin,
                                              ushort* __restrict__ xout,
                                              const int* __restrict__ fill,
                                              const unsigned* __restrict__ bkt,
                                              const float* __restrict__ scale) {
    int n = blockIdx.x * 4 + (threadIdx.x >> 6);
    int lane = threadIdx.x & 63;
    int half = lane >> 5;              // 0: even edges, 1: odd edges
    int fb = lane & 31;                // features fb*8 .. fb*8+7
    const float4* xrow = (const float4*)xin;    // row r = x4[r*32 + fb]
    const unsigned* base = bkt + (size_t)n * CAP;
    int cnt = fill[n];
    float4 uself = xrow[n * 32 + fb];  // early: self-loop row
    float sc = scale[n];               // early: row scale
    f32x2 acc[4];
    #pragma unroll
    for (int i = 0; i < 4; i++) { acc[i][0] = 0.f; acc[i][1] = 0.f; }
    int nsteps = (cnt + 1) >> 1;       // this half processes i = 0..nsteps-1, e = 2i+half
    for (int i0 = 0; i0 < nsteps; i0 += 16) {
        unsigned m[16];
        #pragma unroll
        for (int j = 0; j < 16; j++) {
            int e = 2 * (i0 + j) + half;
            m[j] = (e < cnt) ? base[e] : 0u;     // OOB -> row 0, w 0
        }
        float4 u[16];
        #pragma unroll
        for (int j = 0; j < 16; j++) u[j] = xrow[(int)(m[j] & 0xffffu) * 32 + fb];
        #pragma unroll
        for (int j = 0; j < 16; j++)
            acc8v(acc, u[j], (float)(m[j] >> 16) * (1.0f / 65536.0f));
    }
    float accs[8];
    #pragma unroll
    for (int i = 0; i < 4; i++) { accs[2 * i] = acc[i][0]; accs[2 * i + 1] = acc[i][1]; }
    #pragma unroll
    for (int i = 0; i < 8; i++) accs[i] += __shfl_xor(accs[i], 32);
    if (half == 0) {
        acc8(accs, uself, 1.0f);           // self loop, raw weight 1
        #pragma unroll
        for (int i = 0; i < 8; i++) accs[i] *= sc;
        unsigned p0 = ((unsigned)f2bf(accs[1]) << 16) | f2bf(accs[0]);
        unsigned p1 = ((unsigned)f2bf(accs[3]) << 16) | f2bf(accs[2]);
        unsigned p2 = ((unsigned)f2bf(accs[5]) << 16) | f2bf(accs[4]);
        unsigned p3 = ((unsigned)f2bf(accs[7]) << 16) | f2bf(accs[6]);
        float4 o;
        o.x = __uint_as_float(p0); o.y = __uint_as_float(p1);
        o.z = __uint_as_float(p2); o.w = __uint_as_float(p3);
        ((float4*)xout)[n * 32 + fb] = o;
    }
}

// ------- y[m][o] = PReLU(bias[o] + sum_k A[m][k] W[o][k]) -> BF16, + BN stats -----
// Stats (s, s2) accumulate in f32 from pre-rounding values; y stored bf16 (halves
// the y round-trip traffic: 61MB -> 46MB per layer).
__global__ __launch_bounds__(256) void k_gemm_fused(const short* __restrict__ A,  // NN x 256 bf16
                                                    const short* __restrict__ B,  // 256 x 256 bf16 (W)
                                                    const float* __restrict__ bias,
                                                    const float* __restrict__ pw,
                                                    ushort* __restrict__ yh,      // NN x 256 bf16
                                                    float* __restrict__ sums) {
    constexpr int RT = NN / 16;        // 1875 row tiles
    int w    = threadIdx.x >> 6;       // wave in block
    int lane = threadIdx.x & 63;
    int rt   = blockIdx.x * 4 + w;     // 4 row tiles per block
    int ml   = lane & 15;              // row in tile (A) / col in 16-tile (B, D)
    int q    = lane >> 4;              // quad: A/B k = q*8+j, D row = q*4+r
    bool valid = rt < RT;
    __shared__ float red[2][4][NF];    // [s|s2][wave][col] = 8 KB
    f32x4 acc[16];
    #pragma unroll
    for (int i = 0; i < 16; i++) acc[i] = (f32x4){0.f, 0.f, 0.f, 0.f};
    if (valid) {
        const short* arow = A + (rt * 16 + ml) * NF + q * 8;
        #pragma unroll
        for (int ks = 0; ks < 8; ks++) {
            bf16x8 a = *(const bf16x8*)(arow + ks * 32);
            #pragma unroll
            for (int nt = 0; nt < 16; nt++) {
                bf16x8 b = *(const bf16x8*)(B + (nt * 16 + ml) * NF + ks * 32 + q * 8);
                acc[nt] = __builtin_amdgcn_mfma_f32_16x16x32_bf16(a, b, acc[nt], 0, 0, 0);
            }
        }
    }
    #pragma unroll
    for (int nt = 0; nt < 16; nt++) {
        int col = nt * 16 + ml;
        float s = 0.f, s2 = 0.f;
        if (valid) {
            float bb = bias[col];
            float pc = pw[col];
            #pragma unroll
            for (int r = 0; r < 4; r++) {
                float v = acc[nt][r] + bb;
                v = (v >= 0.f) ? v : pc * v;
                s += v; s2 += v * v;
                yh[(rt * 16 + q * 4 + r) * NF + col] = f2bf(v);
            }
        }
        s  += __shfl_xor(s, 16);  s  += __shfl_xor(s, 32);
        s2 += __shfl_xor(s2, 16); s2 += __shfl_xor(s2, 32);
        if (lane < 16) { red[0][w][col] = s; red[1][w][col] = s2; }
    }
    __syncthreads();
    int t = threadIdx.x;               // t = col, all 256 threads
    float v0 = red[0][0][t] + red[0][1][t] + red[0][2][t] + red[0][3][t];
    float v1 = red[1][0][t] + red[1][1][t] + red[1][2][t] + red[1][3][t];
    atomicAdd(&sums[t], v0);
    atomicAdd(&sums[NF + t], v1);
}

// -- apply BN (scale/shift recomputed per-thread from sums) + dinv, bf16 y -> bf16 x --
__global__ void k_apply_h(const ushort4* __restrict__ yh, const float* __restrict__ sums,
                          const float* __restrict__ gamma, const float* __restrict__ beta,
                          const float* __restrict__ dinv, ushort4* __restrict__ xh) {
    int idx = blockIdx.x * 256 + threadIdx.x;          // ushort4 index (4 bf16)
    if (idx >= NN * (NF / 4)) return;
    int f = (idx & 63) * 4;
    float sc0, sh0, sc1, sh1, sc2, sh2, sc3, sh3;
    bn_ss(sums, gamma, beta, f,     sc0, sh0);
    bn_ss(sums, gamma, beta, f + 1, sc1, sh1);
    bn_ss(sums, gamma, beta, f + 2, sc2, sh2);
    bn_ss(sums, gamma, beta, f + 3, sc3, sh3);
    float di = dinv[idx >> 6];
    ushort4 v = yh[idx];
    ushort4 o;
    o.x = f2bf((bf2f(v.x) * sc0 + sh0) * di);
    o.y = f2bf((bf2f(v.y) * sc1 + sh1) * di);
    o.z = f2bf((bf2f(v.z) * sc2 + sh2) * di);
    o.w = f2bf((bf2f(v.w) * sc3 + sh3) * di);
    xh[idx] = o;
}

// -------- apply BN (per-thread scale/shift): bf16 y -> f32 output -----------------
__global__ void k_apply_out(const ushort4* __restrict__ yh, const float* __restrict__ sums,
                            const float* __restrict__ gamma, const float* __restrict__ beta,
                            float4* __restrict__ out) {
    int idx = blockIdx.x * 256 + threadIdx.x;          // ushort4 index (4 bf16)
    if (idx >= NN * (NF / 4)) return;
    int f = (idx & 63) * 4;
    float sc0, sh0, sc1, sh1, sc2, sh2, sc3, sh3;
    bn_ss(sums, gamma, beta, f,     sc0, sh0);
    bn_ss(sums, gamma, beta, f + 1, sc1, sh1);
    bn_ss(sums, gamma, beta, f + 2, sc2, sh2);
    bn_ss(sums, gamma, beta, f + 3, sc3, sh3);
    ushort4 v = yh[idx];
    float4 o;
    o.x = bf2f(v.x) * sc0 + sh0;
    o.y = bf2f(v.y) * sc1 + sh1;
    o.z = bf2f(v.z) * sc2 + sh2;
    o.w = bf2f(v.w) * sc3 + sh3;
    out[idx] = o;
}

extern "C" void kernel_launch(void* const* d_in, const int* in_sizes, int n_in,
                              void* d_out, int out_size, void* d_ws, size_t ws_size,
                              hipStream_t stream) {
    const float* cell  = (const float*)d_in[0];
    const float* sub   = (const float*)d_in[1];
    const int*   ei    = (const int*)  d_in[2];
    const float* ew    = (const float*)d_in[3];
    const float* W1    = (const float*)d_in[4];
    const float* bias1 = (const float*)d_in[5];
    const float* W2    = (const float*)d_in[6];
    const float* bias2 = (const float*)d_in[7];
    const float* pw    = (const float*)d_in[8];
    const float* gamma = (const float*)d_in[9];
    const float* beta  = (const float*)d_in[10];
    float* out = (float*)d_out;        // reference output dtype is float32
    const int E = in_sizes[3];         // 960000 directed edges

    char* ws = (char*)d_ws;
    size_t off = 0;
    auto alloc = [&](size_t bytes) -> void* {
        void* p = ws + off;
        off = (off + bytes + 255) & ~((size_t)255);
        return p;
    };
    ushort*   xh0  = (ushort*)  alloc((size_t)NN * NF * 2);     // bf16 x ping
    ushort*   xh1  = (ushort*)  alloc((size_t)NN * NF * 2);     // bf16 x pong
    ushort*   yh   = (ushort*)  alloc((size_t)NN * NF * 2);     // bf16 prelu'd gemm out
    ushort*   W1h  = (ushort*)  alloc((size_t)NF * NF * 2);
    ushort*   W2h  = (ushort*)  alloc((size_t)NF * NF * 2);
    unsigned* bkt  = (unsigned*)alloc((size_t)NN * CAP * 4);    // 9.6 MB edge buckets
    int*      fill = (int*)     alloc((size_t)NN * 4);
    float*    s1   = (float*)   alloc((size_t)NN * 4);          // dinv^2
    float*    s2   = (float*)   alloc((size_t)NN * 4);          // dinv
    float*    sums = (float*)   alloc((size_t)2 * NF * 4);

    const int gSU = 118 + 64 + 64;                // 246: init + cvtw1 + cvtw2
    const int gS8 = ((E + SLICE - 1) / SLICE) * 8;// (slice, range) pairs
    const int gDC = NN / 8;                       // 3750 blocks, 8 nodes each
    const int gV4 = (NN * NF / 4 + 255) / 256;    // 7500
    const int gP  = NN / 4;                       // 7500 blocks, 1 wave/node
    const int gG  = (NN / 16 + 3) / 4;            // 469 blocks x 4 waves

    k_setup<<<gSU, 256, 0, stream>>>(fill, sums, (const float4*)W1, (ushort4*)W1h,
                                     (const float4*)W2, (ushort4*)W2h);
    k_scatter8<<<gS8, 256, 0, stream>>>(ei, ew, fill, bkt, E);
    k_degcat<<<gDC, 256, 0, stream>>>(bkt, fill, (const float4*)cell, (const float4*)sub,
                                      s1, s2, (ushort4*)xh0);

    // ---------------- layer 1 ----------------
    k_prop<<<gP, 256, 0, stream>>>(xh0, xh1, fill, bkt, s1);
    k_prop<<<gP, 256, 0, stream>>>(xh1, xh0, fill, bkt, s1);
    k_prop<<<gP, 256, 0, stream>>>(xh0, xh1, fill, bkt, s2);
    k_gemm_fused<<<gG, 256, 0, stream>>>((const short*)xh1, (const short*)W1h, bias1, pw, yh, sums);
    k_apply_h<<<gV4, 256, 0, stream>>>((const ushort4*)yh, sums, gamma, beta, s2, (ushort4*)xh0);
    k_zero_stats<<<1, 512, 0, stream>>>(sums);

    // ---------------- layer 2 ----------------
    k_prop<<<gP, 256, 0, stream>>>(xh0, xh1, fill, bkt, s1);
    k_prop<<<gP, 256, 0, stream>>>(xh1, xh0, fill, bkt, s1);
    k_prop<<<gP, 256, 0, stream>>>(xh0, xh1, fill, bkt, s2);
    k_gemm_fused<<<gG, 256, 0, stream>>>((const short*)xh1, (const short*)W2h, bias2, pw, yh, sums);
    k_apply_out<<<gV4, 256, 0, stream>>>((const ushort4*)yh, sums, gamma, beta, (float4*)out);
}

// Round 13
// 607.994 us; speedup vs baseline: 1.2608x; 1.0009x over previous
//
#include <hip/hip_runtime.h>
#include <hip/hip_bf16.h>

constexpr int NN    = 30000;   // total nodes
constexpr int NCELL = 66;
constexpr int NF    = 256;     // features
constexpr int CAP   = 80;      // bucket capacity per col (in-deg mean 32, P(>80)~1e-8)
constexpr float EPS = 1e-5f;

using bf16x8 = __attribute__((ext_vector_type(8))) short;   // 8 bf16 = 4 VGPRs
using f32x4  = __attribute__((ext_vector_type(4))) float;
using f32x2  = __attribute__((ext_vector_type(2))) float;

__device__ __forceinline__ unsigned short f2bf(float f) {
    __hip_bfloat16 h = __float2bfloat16(f);   // RNE
    return *reinterpret_cast<unsigned short*>(&h);
}
__device__ __forceinline__ float bf2f(unsigned short u) {
    return __uint_as_float(((unsigned)u) << 16);
}
// accumulate 8 bf16 features packed in a float4 (bit halves) into 4x f32x2 (pk_fma)
__device__ __forceinline__ void acc8v(f32x2* acc, float4 u, float w) {
    unsigned a = __float_as_uint(u.x), b = __float_as_uint(u.y);
    unsigned c = __float_as_uint(u.z), d = __float_as_uint(u.w);
    f32x2 wv; wv[0] = w; wv[1] = w;
    f32x2 e0; e0[0] = __uint_as_float(a << 16); e0[1] = __uint_as_float(a & 0xffff0000u);
    f32x2 e1; e1[0] = __uint_as_float(b << 16); e1[1] = __uint_as_float(b & 0xffff0000u);
    f32x2 e2; e2[0] = __uint_as_float(c << 16); e2[1] = __uint_as_float(c & 0xffff0000u);
    f32x2 e3; e3[0] = __uint_as_float(d << 16); e3[1] = __uint_as_float(d & 0xffff0000u);
    acc[0] += wv * e0;
    acc[1] += wv * e1;
    acc[2] += wv * e2;
    acc[3] += wv * e3;
}
// scalar variant for epilogue self-loop add
__device__ __forceinline__ void acc8(float* acc, float4 u, float w) {
    unsigned a = __float_as_uint(u.x), b = __float_as_uint(u.y);
    unsigned c = __float_as_uint(u.z), d = __float_as_uint(u.w);
    acc[0] += w * __uint_as_float(a << 16);
    acc[1] += w * __uint_as_float(a & 0xffff0000u);
    acc[2] += w * __uint_as_float(b << 16);
    acc[3] += w * __uint_as_float(b & 0xffff0000u);
    acc[4] += w * __uint_as_float(c << 16);
    acc[5] += w * __uint_as_float(c & 0xffff0000u);
    acc[6] += w * __uint_as_float(d << 16);
    acc[7] += w * __uint_as_float(d & 0xffff0000u);
}
// recompute BN scale/shift for one col from raw sums (deterministic, ~10 ops)
__device__ __forceinline__ void bn_ss(const float* sums, const float* gamma,
                                      const float* beta, int col, float& sc, float& sh) {
    float mean = sums[col] * (1.0f / (float)NN);
    float var  = sums[NF + col] * (1.0f / (float)NN) - mean * mean;
    if (var < 0.f) var = 0.f;
    float istd = rsqrtf(var + EPS);
    sc = gamma[col] * istd;
    sh = beta[col] - mean * sc;
}

// -- setup: fill/sumsA/sumsB = 0 (blocks 0..117), cvt W1 (118..181), W2 (182..245) --
__global__ void k_setup(int* fill, float* sumsA, float* sumsB,
                        const float4* __restrict__ W1, ushort4* __restrict__ W1h,
                        const float4* __restrict__ W2, ushort4* __restrict__ W2h) {
    int b = blockIdx.x;
    if (b < 118) {
        int i = b * 256 + threadIdx.x;
        if (i < NN) fill[i] = 0;
        if (i < 2 * NF) { sumsA[i] = 0.0f; sumsB[i] = 0.0f; }
    } else {
        const float4* src = (b < 182) ? W1 : W2;
        ushort4* dst      = (b < 182) ? W1h : W2h;
        int idx = (b - ((b < 182) ? 118 : 182)) * 256 + threadIdx.x;
        if (idx < NF * NF / 4) {
            float4 v = src[idx];
            ushort4 o;
            o.x = f2bf(v.x); o.y = f2bf(v.y); o.z = f2bf(v.z); o.w = f2bf(v.w);
            dst[idx] = o;
        }
    }
}

// ------ scatter, col-range partitioned: block = (edge-slice, range r=bid&7) -------
// Range r owns cols [r*3750,(r+1)*3750) -> each bucket line written by blocks of one
// range; with blockIdx%8 -> XCD round-robin those share an L2 -> lines fill in-cache
// and write back whole (R8->R9 differential: part of the 654->624 win). CACHED
// stores. col read 8x (L3-resident); row/ew only under the range test.
constexpr int SLICE = 2048;
__global__ __launch_bounds__(256) void k_scatter8(const int* __restrict__ ei,
                                                  const float* __restrict__ ew,
                                                  int* fill, unsigned* __restrict__ bkt,
                                                  int E) {
    int r  = blockIdx.x & 7;
    int s  = blockIdx.x >> 3;
    int lo = r * (NN / 8);
    int hi = lo + (NN / 8);
    int e0 = s * SLICE;
    int e1 = e0 + SLICE; if (e1 > E) e1 = E;
    for (int e = e0 + threadIdx.x; e < e1; e += 256) {
        int col = ei[E + e];
        if (col >= lo && col < hi) {
            int row  = ei[e];
            float wv = ew[e];
            unsigned q = (unsigned)(wv * 65536.0f);   // trunc; ew<1 => q<=65535
            int pos = atomicAdd(&fill[col], 1);
            bkt[(size_t)col * CAP + pos] = ((unsigned)row) | (q << 16);
        }
    }
}

// --- fused deg + concat: 8 nodes/block; 32-lane group: degree-reduce -> prescale ---
// group g owns node n = bid*8+g: sum ewq over bucket (32-lane strided + shfl tree),
// emit s1 = dinv^2, s2 = dinv; then the same 32 lanes convert/prescale node n's
// 256-feat row (64 float4, 2 per lane) using the just-computed dinv (no round-trip).
__global__ __launch_bounds__(256) void k_degcat(const unsigned* __restrict__ bkt,
                                                const int* __restrict__ fill,
                                                const float4* __restrict__ cell,
                                                const float4* __restrict__ sub,
                                                float* __restrict__ s1,
                                                float* __restrict__ s2,
                                                ushort4* __restrict__ xh) {
    int g  = threadIdx.x >> 5;          // group 0..7
    int l  = threadIdx.x & 31;          // lane in group
    int n  = blockIdx.x * 8 + g;
    int cnt = fill[n];
    const unsigned* p = bkt + (size_t)n * CAP;
    unsigned sq = 0;
    for (int e = l; e < cnt; e += 32) sq += (p[e] >> 16);
    sq += __shfl_xor((int)sq, 1);
    sq += __shfl_xor((int)sq, 2);
    sq += __shfl_xor((int)sq, 4);
    sq += __shfl_xor((int)sq, 8);
    sq += __shfl_xor((int)sq, 16);
    float deg = 1.0f + (float)sq * (1.0f / 65536.0f);
    float di = rsqrtf(deg);
    if (l == 0) { s2[n] = di; s1[n] = di * di; }
    const int CELL4 = NCELL * (NF / 4);
    #pragma unroll
    for (int k = 0; k < 2; k++) {
        int gidx = n * 64 + l + 32 * k;          // float4 index in [NN][256]
        float4 v = (gidx < CELL4) ? cell[gidx] : sub[gidx - CELL4];
        ushort4 o;
        o.x = f2bf(v.x * di); o.y = f2bf(v.y * di);
        o.z = f2bf(v.z * di); o.w = f2bf(v.w * di);
        xh[gidx] = o;
    }
}

// ------------- one hop: t = (A+I) x, then row-scale; bf16 in/out, f32 accum --------
// R12-verified (59us, FETCH 190MB = 1.55x the 8-XCD compulsory replication floor,
// fabric ~3.2TB/s). Fabric-roofline-pinned: locality (R2/4/6-8), latency (R5),
// and concurrency (R12 depth-16) theories all falsified by measurement. Do not
// touch without new counter evidence.
__global__ __launch_bounds__(256) void k_prop(const ushort* __restrict__ xin,
                                              ushort* __restrict__ xout,
                                              const int* __restrict__ fill,
                                              const unsigned* __restrict__ bkt,
                                              const float* __restrict__ scale) {
    int n = blockIdx.x * 4 + (threadIdx.x >> 6);
    int lane = threadIdx.x & 63;
    int half = lane >> 5;              // 0: even edges, 1: odd edges
    int fb = lane & 31;                // features fb*8 .. fb*8+7
    const float4* xrow = (const float4*)xin;    // row r = x4[r*32 + fb]
    const unsigned* base = bkt + (size_t)n * CAP;
    int cnt = fill[n];
    float4 uself = xrow[n * 32 + fb];  // early: self-loop row
    float sc = scale[n];               // early: row scale
    f32x2 acc[4];
    #pragma unroll
    for (int i = 0; i < 4; i++) { acc[i][0] = 0.f; acc[i][1] = 0.f; }
    int nsteps = (cnt + 1) >> 1;       // this half processes i = 0..nsteps-1, e = 2i+half
    for (int i0 = 0; i0 < nsteps; i0 += 16) {
        unsigned m[16];
        #pragma unroll
        for (int j = 0; j < 16; j++) {
            int e = 2 * (i0 + j) + half;
            m[j] = (e < cnt) ? base[e] : 0u;     // OOB -> row 0, w 0
        }
        float4 u[16];
        #pragma unroll
        for (int j = 0; j < 16; j++) u[j] = xrow[(int)(m[j] & 0xffffu) * 32 + fb];
        #pragma unroll
        for (int j = 0; j < 16; j++)
            acc8v(acc, u[j], (float)(m[j] >> 16) * (1.0f / 65536.0f));
    }
    float accs[8];
    #pragma unroll
    for (int i = 0; i < 4; i++) { accs[2 * i] = acc[i][0]; accs[2 * i + 1] = acc[i][1]; }
    #pragma unroll
    for (int i = 0; i < 8; i++) accs[i] += __shfl_xor(accs[i], 32);
    if (half == 0) {
        acc8(accs, uself, 1.0f);           // self loop, raw weight 1
        #pragma unroll
        for (int i = 0; i < 8; i++) accs[i] *= sc;
        unsigned p0 = ((unsigned)f2bf(accs[1]) << 16) | f2bf(accs[0]);
        unsigned p1 = ((unsigned)f2bf(accs[3]) << 16) | f2bf(accs[2]);
        unsigned p2 = ((unsigned)f2bf(accs[5]) << 16) | f2bf(accs[4]);
        unsigned p3 = ((unsigned)f2bf(accs[7]) << 16) | f2bf(accs[6]);
        float4 o;
        o.x = __uint_as_float(p0); o.y = __uint_as_float(p1);
        o.z = __uint_as_float(p2); o.w = __uint_as_float(p3);
        ((float4*)xout)[n * 32 + fb] = o;
    }
}

// ------- y[m][o] = PReLU(bias[o] + sum_k A[m][k] W[o][k]) -> BF16, + BN stats -----
// Stats (s, s2) accumulate in f32 from pre-rounding values; y stored bf16 (halves
// the y round-trip traffic: 61MB -> 46MB per layer).
__global__ __launch_bounds__(256) void k_gemm_fused(const short* __restrict__ A,  // NN x 256 bf16
                                                    const short* __restrict__ B,  // 256 x 256 bf16 (W)
                                                    const float* __restrict__ bias,
                                                    const float* __restrict__ pw,
                                                    ushort* __restrict__ yh,      // NN x 256 bf16
                                                    float* __restrict__ sums) {
    constexpr int RT = NN / 16;        // 1875 row tiles
    int w    = threadIdx.x >> 6;       // wave in block
    int lane = threadIdx.x & 63;
    int rt   = blockIdx.x * 4 + w;     // 4 row tiles per block
    int ml   = lane & 15;              // row in tile (A) / col in 16-tile (B, D)
    int q    = lane >> 4;              // quad: A/B k = q*8+j, D row = q*4+r
    bool valid = rt < RT;
    __shared__ float red[2][4][NF];    // [s|s2][wave][col] = 8 KB
    f32x4 acc[16];
    #pragma unroll
    for (int i = 0; i < 16; i++) acc[i] = (f32x4){0.f, 0.f, 0.f, 0.f};
    if (valid) {
        const short* arow = A + (rt * 16 + ml) * NF + q * 8;
        #pragma unroll
        for (int ks = 0; ks < 8; ks++) {
            bf16x8 a = *(const bf16x8*)(arow + ks * 32);
            #pragma unroll
            for (int nt = 0; nt < 16; nt++) {
                bf16x8 b = *(const bf16x8*)(B + (nt * 16 + ml) * NF + ks * 32 + q * 8);
                acc[nt] = __builtin_amdgcn_mfma_f32_16x16x32_bf16(a, b, acc[nt], 0, 0, 0);
            }
        }
    }
    #pragma unroll
    for (int nt = 0; nt < 16; nt++) {
        int col = nt * 16 + ml;
        float s = 0.f, s2 = 0.f;
        if (valid) {
            float bb = bias[col];
            float pc = pw[col];
            #pragma unroll
            for (int r = 0; r < 4; r++) {
                float v = acc[nt][r] + bb;
                v = (v >= 0.f) ? v : pc * v;
                s += v; s2 += v * v;
                yh[(rt * 16 + q * 4 + r) * NF + col] = f2bf(v);
            }
        }
        s  += __shfl_xor(s, 16);  s  += __shfl_xor(s, 32);
        s2 += __shfl_xor(s2, 16); s2 += __shfl_xor(s2, 32);
        if (lane < 16) { red[0][w][col] = s; red[1][w][col] = s2; }
    }
    __syncthreads();
    int t = threadIdx.x;               // t = col, all 256 threads
    float v0 = red[0][0][t] + red[0][1][t] + red[0][2][t] + red[0][3][t];
    float v1 = red[1][0][t] + red[1][1][t] + red[1][2][t] + red[1][3][t];
    atomicAdd(&sums[t], v0);
    atomicAdd(&sums[NF + t], v1);
}

// -- apply BN (scale/shift recomputed per-thread from sums) + dinv, bf16 y -> bf16 x --
// 2x ushort4 per thread: amortizes the bn_ss recompute over 8 cols, 16B loads.
__global__ void k_apply_h(const ushort4* __restrict__ yh, const float* __restrict__ sums,
                          const float* __restrict__ gamma, const float* __restrict__ beta,
                          const float* __restrict__ dinv, ushort4* __restrict__ xh) {
    int t = blockIdx.x * 256 + threadIdx.x;            // pair index (8 bf16)
    if (t >= NN * (NF / 8)) return;
    int idx = t * 2;                                   // first ushort4 index
    float di = dinv[idx >> 6];
    #pragma unroll
    for (int k = 0; k < 2; k++) {
        int f = ((idx + k) & 63) * 4;
        float sc0, sh0, sc1, sh1, sc2, sh2, sc3, sh3;
        bn_ss(sums, gamma, beta, f,     sc0, sh0);
        bn_ss(sums, gamma, beta, f + 1, sc1, sh1);
        bn_ss(sums, gamma, beta, f + 2, sc2, sh2);
        bn_ss(sums, gamma, beta, f + 3, sc3, sh3);
        ushort4 v = yh[idx + k];
        ushort4 o;
        o.x = f2bf((bf2f(v.x) * sc0 + sh0) * di);
        o.y = f2bf((bf2f(v.y) * sc1 + sh1) * di);
        o.z = f2bf((bf2f(v.z) * sc2 + sh2) * di);
        o.w = f2bf((bf2f(v.w) * sc3 + sh3) * di);
        xh[idx + k] = o;
    }
}

// -------- apply BN (per-thread scale/shift): bf16 y -> f32 output -----------------
// 2x ushort4 per thread (reads 16B, writes 32B).
__global__ void k_apply_out(const ushort4* __restrict__ yh, const float* __restrict__ sums,
                            const float* __restrict__ gamma, const float* __restrict__ beta,
                            float4* __restrict__ out) {
    int t = blockIdx.x * 256 + threadIdx.x;            // pair index (8 bf16)
    if (t >= NN * (NF / 8)) return;
    int idx = t * 2;                                   // first ushort4 index
    #pragma unroll
    for (int k = 0; k < 2; k++) {
        int f = ((idx + k) & 63) * 4;
        float sc0, sh0, sc1, sh1, sc2, sh2, sc3, sh3;
        bn_ss(sums, gamma, beta, f,     sc0, sh0);
        bn_ss(sums, gamma, beta, f + 1, sc1, sh1);
        bn_ss(sums, gamma, beta, f + 2, sc2, sh2);
        bn_ss(sums, gamma, beta, f + 3, sc3, sh3);
        ushort4 v = yh[idx + k];
        float4 o;
        o.x = bf2f(v.x) * sc0 + sh0;
        o.y = bf2f(v.y) * sc1 + sh1;
        o.z = bf2f(v.z) * sc2 + sh2;
        o.w = bf2f(v.w) * sc3 + sh3;
        out[idx + k] = o;
    }
}

extern "C" void kernel_launch(void* const* d_in, const int* in_sizes, int n_in,
                              void* d_out, int out_size, void* d_ws, size_t ws_size,
                              hipStream_t stream) {
    const float* cell  = (const float*)d_in[0];
    const float* sub   = (const float*)d_in[1];
    const int*   ei    = (const int*)  d_in[2];
    const float* ew    = (const float*)d_in[3];
    const float* W1    = (const float*)d_in[4];
    const float* bias1 = (const float*)d_in[5];
    const float* W2    = (const float*)d_in[6];
    const float* bias2 = (const float*)d_in[7];
    const float* pw    = (const float*)d_in[8];
    const float* gamma = (const float*)d_in[9];
    const float* beta  = (const float*)d_in[10];
    float* out = (float*)d_out;        // reference output dtype is float32
    const int E = in_sizes[3];         // 960000 directed edges

    char* ws = (char*)d_ws;
    size_t off = 0;
    auto alloc = [&](size_t bytes) -> void* {
        void* p = ws + off;
        off = (off + bytes + 255) & ~((size_t)255);
        return p;
    };
    ushort*   xh0  = (ushort*)  alloc((size_t)NN * NF * 2);     // bf16 x ping
    ushort*   xh1  = (ushort*)  alloc((size_t)NN * NF * 2);     // bf16 x pong
    ushort*   yh   = (ushort*)  alloc((size_t)NN * NF * 2);     // bf16 prelu'd gemm out
    ushort*   W1h  = (ushort*)  alloc((size_t)NF * NF * 2);
    ushort*   W2h  = (ushort*)  alloc((size_t)NF * NF * 2);
    unsigned* bkt  = (unsigned*)alloc((size_t)NN * CAP * 4);    // 9.6 MB edge buckets
    int*      fill = (int*)     alloc((size_t)NN * 4);
    float*    s1   = (float*)   alloc((size_t)NN * 4);          // dinv^2
    float*    s2   = (float*)   alloc((size_t)NN * 4);          // dinv
    float*    sumsA = (float*)  alloc((size_t)2 * NF * 4);      // layer-1 BN stats
    float*    sumsB = (float*)  alloc((size_t)2 * NF * 4);      // layer-2 BN stats

    const int gSU = 118 + 64 + 64;                // 246: init + cvtw1 + cvtw2
    const int gS8 = ((E + SLICE - 1) / SLICE) * 8;// (slice, range) pairs
    const int gDC = NN / 8;                       // 3750 blocks, 8 nodes each
    const int gV8 = (NN * NF / 8 + 255) / 256;    // 3750 (pair-width apply)
    const int gP  = NN / 4;                       // 7500 blocks, 1 wave/node
    const int gG  = (NN / 16 + 3) / 4;            // 469 blocks x 4 waves

    k_setup<<<gSU, 256, 0, stream>>>(fill, sumsA, sumsB, (const float4*)W1, (ushort4*)W1h,
                                     (const float4*)W2, (ushort4*)W2h);
    k_scatter8<<<gS8, 256, 0, stream>>>(ei, ew, fill, bkt, E);
    k_degcat<<<gDC, 256, 0, stream>>>(bkt, fill, (const float4*)cell, (const float4*)sub,
                                      s1, s2, (ushort4*)xh0);

    // ---------------- layer 1 ----------------
    k_prop<<<gP, 256, 0, stream>>>(xh0, xh1, fill, bkt, s1);
    k_prop<<<gP, 256, 0, stream>>>(xh1, xh0, fill, bkt, s1);
    k_prop<<<gP, 256, 0, stream>>>(xh0, xh1, fill, bkt, s2);
    k_gemm_fused<<<gG, 256, 0, stream>>>((const short*)xh1, (const short*)W1h, bias1, pw, yh, sumsA);
    k_apply_h<<<gV8, 256, 0, stream>>>((const ushort4*)yh, sumsA, gamma, beta, s2, (ushort4*)xh0);

    // ---------------- layer 2 ----------------
    k_prop<<<gP, 256, 0, stream>>>(xh0, xh1, fill, bkt, s1);
    k_prop<<<gP, 256, 0, stream>>>(xh1, xh0, fill, bkt, s1);
    k_prop<<<gP, 256, 0, stream>>>(xh0, xh1, fill, bkt, s2);
    k_gemm_fused<<<gG, 256, 0, stream>>>((const short*)xh1, (const short*)W2h, bias2, pw, yh, sumsB);
    k_apply_out<<<gV8, 256, 0, stream>>>((const ushort4*)yh, sumsB, gamma, beta, (float4*)out);
}